// Round 6
// baseline (463.278 us; speedup 1.0000x reference)
//
#include <hip/hip_runtime.h>
#include <math.h>

// Problem constants: B=2, T=2048, E=1024, H=16, D=64; M = B*T = 4096
#define MM   4096
#define TT   2048
#define HH   16

typedef __bf16 bf16x8 __attribute__((ext_vector_type(8)));
typedef float f32x4 __attribute__((ext_vector_type(4)));

// async global->LDS, 16B per lane; LDS dest = wave-uniform base + lane*16
__device__ __forceinline__ void g2l16(const void* g, void* l) {
    __builtin_amdgcn_global_load_lds(
        (__attribute__((address_space(1))) void*)g,
        (__attribute__((address_space(3))) void*)l, 16, 0, 0);
}

// ---- raw transcendentals (guarded; libm fallback). Without -ffast-math the
// libm versions lower to multi-instruction OCML guard sequences — 3-4x cost.
#if __has_builtin(__builtin_amdgcn_exp2f)
__device__ __forceinline__ float fexp2(float x) { return __builtin_amdgcn_exp2f(x); }
#else
__device__ __forceinline__ float fexp2(float x) { return exp2f(x); }
#endif
#if __has_builtin(__builtin_amdgcn_logf)
__device__ __forceinline__ float flog2(float x) { return __builtin_amdgcn_logf(x); }
#else
__device__ __forceinline__ float flog2(float x) { return log2f(x); }
#endif
#if __has_builtin(__builtin_amdgcn_sqrtf)
__device__ __forceinline__ float fsqrt_(float x) { return __builtin_amdgcn_sqrtf(x); }
#else
__device__ __forceinline__ float fsqrt_(float x) { return sqrtf(x); }
#endif
#if __has_builtin(__builtin_amdgcn_rcpf)
__device__ __forceinline__ float frcp_(float x) { return __builtin_amdgcn_rcpf(x); }
#else
__device__ __forceinline__ float frcp_(float x) { return 1.0f / x; }
#endif
#if __has_builtin(__builtin_amdgcn_rsqf)
__device__ __forceinline__ float frsq_(float x) { return __builtin_amdgcn_rsqf(x); }
#else
__device__ __forceinline__ float frsq_(float x) { return rsqrtf(x); }
#endif

// fast GELU (tanh form, abs err ~1e-3; ref tolerance 0.25 and downstream
// weights are 0.02-scale -> negligible). Replaces libm erff (~35 VALU ops).
__device__ __forceinline__ float gelu_f(float x) {
    float u = 0.7978845608028654f * fmaf(0.044715f * x, x * x, x);
    u = fminf(fmaxf(u, -15.f), 15.f);
    float t = fexp2(-2.885390081777927f * u);     // e^{-2u}
    return 0.5f * x * (1.f + (1.f - t) * frcp_(1.f + t));
}

// ---------------------------------------------------------------- reductions
__device__ __forceinline__ float blockSum256(float v, volatile float* sb) {
    int lane = threadIdx.x & 63, w = threadIdx.x >> 6;
#pragma unroll
    for (int o = 32; o; o >>= 1) v += __shfl_xor(v, o);
    if (lane == 0) sb[w] = v;
    __syncthreads();
    v = sb[0] + sb[1] + sb[2] + sb[3];
    __syncthreads();
    return v;
}

// ---------------------------------------------------------------- block_norm -> bf16 (ldo-wide, zero pad)
__global__ __launch_bounds__(256) void block_norm_bf_k(
    const float* __restrict__ in, int ld,
    __bf16* __restrict__ out, int ldo,
    const float* __restrict__ lw, const float* __restrict__ lb,
    const float* __restrict__ curv)
{
    int row = blockIdx.x;
    const float* x = in + (size_t)row * ld;
    __bf16* o = out + (size_t)row * ldo;
    __shared__ float sb[4];
    int tid = threadIdx.x;
    float v[4]; float s1 = 0.f, s2 = 0.f;
#pragma unroll
    for (int r = 0; r < 4; r++) {
        float t = x[tid + 256 * r];
        v[r] = t; s1 += t; s2 += t * t;
    }
    s1 = blockSum256(s1, sb);
    s2 = blockSum256(s2, sb);
    float mean = s1 * (1.f / 1024.f);
    float var  = s2 * (1.f / 1024.f) - mean * mean;
    float rs = rsqrtf(var + 1e-5f);
    float y[4]; float ssq = 0.f;
#pragma unroll
    for (int r = 0; r < 4; r++) {
        int i = tid + 256 * r;
        float t = (v[r] - mean) * rs * lw[i] + lb[i];
        y[r] = t; ssq += t * t;
    }
    ssq = blockSum256(ssq, sb);
#pragma unroll
    for (int r = 0; r < 4; r++) o[1 + tid + 256 * r] = (__bf16)y[r];
    if (tid == 0) o[0] = (__bf16)sqrtf(expf(*curv) + ssq);
    if (tid < ldo - 1025) o[1025 + tid] = (__bf16)0.f;   // zero pad cols 1025..ldo-1
}

// ---------------------------------------------------------------- row x0 (fp32, final output)
__global__ __launch_bounds__(256) void row_x0_k(
    float* __restrict__ buf, int stride, int n, const float* __restrict__ curv)
{
    int row = blockIdx.x;
    float* base = buf + (size_t)row * stride;
    __shared__ float sb[4];
    float s = 0.f;
    for (int i = threadIdx.x; i < n; i += 256) { float t = base[1 + i]; s += t * t; }
    s = blockSum256(s, sb);
    if (threadIdx.x == 0) base[0] = sqrtf(expf(*curv) + s);
}

// ---------------------------------------------------------------- h tail (3 ragged cols) + x0 + pad (stride 4224)
__global__ __launch_bounds__(256) void row_x0_tail_k(
    __bf16* __restrict__ h,
    const __bf16* __restrict__ ln,      // ln2, stride 1088 (zero-padded past 1025)
    const __bf16* __restrict__ Bt,      // meT, stride 1088
    const float* __restrict__ bias,     // b_me (4099)
    const float* __restrict__ curv)
{
    int row = blockIdx.x;
    __bf16* base = h + (size_t)row * 4224;
    const __bf16* lnr = ln + (size_t)row * 1088;
    const __bf16* B0 = Bt + (size_t)4096 * 1088;
    const __bf16* B1 = Bt + (size_t)4097 * 1088;
    const __bf16* B2 = Bt + (size_t)4098 * 1088;
    __shared__ float sb[4];
    float d0 = 0.f, d1 = 0.f, d2 = 0.f;
    for (int i = threadIdx.x; i < 1088; i += 256) {
        float a = (float)lnr[i];
        d0 += a * (float)B0[i];
        d1 += a * (float)B1[i];
        d2 += a * (float)B2[i];
    }
    d0 = blockSum256(d0, sb);
    d1 = blockSum256(d1, sb);
    d2 = blockSum256(d2, sb);
    float t3[3] = {d0 + bias[4096], d1 + bias[4097], d2 + bias[4098]};
    float ssq_t = 0.f;
#pragma unroll
    for (int j = 0; j < 3; j++) {
        float v = gelu_f(t3[j]);
        t3[j] = v; ssq_t += v * v;
    }
    if (threadIdx.x == 0) {
        base[1 + 4096] = (__bf16)t3[0];
        base[1 + 4097] = (__bf16)t3[1];
        base[1 + 4098] = (__bf16)t3[2];
    }
    float s = 0.f;
    for (int i = threadIdx.x; i < 4096; i += 256) { float t = (float)base[1 + i]; s += t * t; }
    s = blockSum256(s, sb) + ssq_t;
    if (threadIdx.x == 0) base[0] = (__bf16)sqrtf(expf(*curv) + s);
    if (threadIdx.x < 124) base[4100 + threadIdx.x] = (__bf16)0.f;  // zero pad 4100..4223
}

// ---------------------------------------------------------------- weight convert + transpose
__global__ __launch_bounds__(256) void wt_k(
    const float* __restrict__ W, int K, int N,
    __bf16* __restrict__ Wt, int Kp)
{
    __shared__ float s[32][33];
    int tx = threadIdx.x & 31, ty = threadIdx.x >> 5;    // 32 x 8
    int k0 = blockIdx.x * 32, n0 = blockIdx.y * 32;
#pragma unroll
    for (int r = 0; r < 4; r++) {
        int k = k0 + ty + 8 * r, n = n0 + tx;
        s[ty + 8 * r][tx] = (k < K && n < N) ? W[(size_t)k * N + n] : 0.f;
    }
    __syncthreads();
#pragma unroll
    for (int r = 0; r < 4; r++) {
        int n = n0 + ty + 8 * r, k = k0 + tx;
        if (n < N) Wt[(size_t)n * Kp + k] = (__bf16)s[tx][ty + 8 * r];
    }
}

// ---------------------------------------------------------------- bf16 MFMA GEMM 256x256, BK=64, 4-phase
// XCD-chunked block remap (see R3 notes). Requires gridDim.y%4==0 && gridDim.x%2==0.
template<bool BIAS, bool GELU, bool OUTBF>
__global__ __launch_bounds__(512, 2) void mgemm256_k(
    const __bf16* __restrict__ A, int lda,
    const __bf16* __restrict__ Bt, int ldb, int NB,   // NB = valid rows of Bt (row clamp)
    const float* __restrict__ bias,
    void* __restrict__ Cout, int ldc,
    int N, int Kp)                                     // Kp multiple of 64
{
    __shared__ __bf16 sAB[65536];   // [A db0 |A db1 |B db0 |B db1] x 16384 elems
    const int tid = threadIdx.x;
    const int w = tid >> 6, lane = tid & 63;
    const int wm = w >> 2, wn = w & 3;
    const int lr = lane & 15, lq = lane >> 4;

    const int lin = blockIdx.y * gridDim.x + blockIdx.x;
    const int xcd = lin & 7, loc = lin >> 3;
    const int LN = gridDim.x >> 1, LM = gridDim.y >> 2;
    const int mt = (xcd >> 1) * LM + loc / LN;
    const int nt = (xcd & 1) * LN + loc % LN;
    const int m0 = mt * 256, n0 = nt * 256;

    const int rr  = tid >> 3;
    const int csw = ((tid & 7) ^ (rr & 7)) << 3;   // elems
    const __bf16* gA[4]; const __bf16* gB[4];
#pragma unroll
    for (int c = 0; c < 4; c++) {
        gA[c] = A + (size_t)(m0 + c * 64 + rr) * lda + csw;
        int rb = n0 + c * 64 + rr; rb = (rb < NB) ? rb : (NB - 1);
        gB[c] = Bt + (size_t)rb * ldb + csw;
    }
    __bf16* lA = sAB + (w << 9);            // + db*16384 + c*4096
    __bf16* lB = sAB + 32768 + (w << 9);

    const int off0 = (lq * 8) ^ ((lr & 7) << 3);
    const int off1 = off0 ^ 32;
    const int arow = wm * 128 + lr;
    const int brow = wn * 64 + lr;

    f32x4 zero = {0.f, 0.f, 0.f, 0.f};
    f32x4 acc[8][4];
#pragma unroll
    for (int i = 0; i < 8; i++)
#pragma unroll
        for (int j = 0; j < 4; j++) acc[i][j] = zero;

    // prologue: stage K-tile 0 -> db0
#pragma unroll
    for (int c = 0; c < 4; c++) {
        g2l16(gA[c], lA + c * 4096);
        g2l16(gB[c], lB + c * 4096);
    }
    asm volatile("s_waitcnt vmcnt(0)" ::: "memory");
    __builtin_amdgcn_s_barrier();

    const int NT = Kp >> 6;
    for (int kt = 0; kt < NT; ++kt) {
        const int cur = kt & 1;
        const __bf16* pA = sAB + cur * 16384;
        const __bf16* pB = sAB + 32768 + cur * 16384;
        bf16x8 af[4][2], bfr[4][2];

        // ---- phase 1: issue next-tile stage early; read A half0 + B[0..1]; MFMA q00
        if (kt + 1 < NT) {
            const int ko = (kt + 1) << 6;
            __bf16* dA = lA + (cur ^ 1) * 16384;
            __bf16* dB = lB + (cur ^ 1) * 16384;
#pragma unroll
            for (int c = 0; c < 4; c++) {
                g2l16(gA[c] + ko, dA + c * 4096);
                g2l16(gB[c] + ko, dB + c * 4096);
            }
        }
#pragma unroll
        for (int i = 0; i < 4; i++) {
            const __bf16* r = pA + (arow + i * 16) * 64;
            af[i][0] = *(const bf16x8*)(r + off0);
            af[i][1] = *(const bf16x8*)(r + off1);
        }
#pragma unroll
        for (int j = 0; j < 2; j++) {
            const __bf16* r = pB + (brow + j * 16) * 64;
            bfr[j][0] = *(const bf16x8*)(r + off0);
            bfr[j][1] = *(const bf16x8*)(r + off1);
        }
        __builtin_amdgcn_s_barrier();
        __builtin_amdgcn_s_setprio(1);
#pragma unroll
        for (int ks = 0; ks < 2; ks++)
#pragma unroll
            for (int i = 0; i < 4; i++)
#pragma unroll
                for (int j = 0; j < 2; j++)
                    acc[i][j] = __builtin_amdgcn_mfma_f32_16x16x32_bf16(af[i][ks], bfr[j][ks], acc[i][j], 0, 0, 0);
        __builtin_amdgcn_s_setprio(0);
        __builtin_amdgcn_s_barrier();

        // ---- phase 2: read B[2..3]; MFMA q01
#pragma unroll
        for (int j = 2; j < 4; j++) {
            const __bf16* r = pB + (brow + j * 16) * 64;
            bfr[j][0] = *(const bf16x8*)(r + off0);
            bfr[j][1] = *(const bf16x8*)(r + off1);
        }
        __builtin_amdgcn_s_barrier();
        __builtin_amdgcn_s_setprio(1);
#pragma unroll
        for (int ks = 0; ks < 2; ks++)
#pragma unroll
            for (int i = 0; i < 4; i++)
#pragma unroll
                for (int j = 2; j < 4; j++)
                    acc[i][j] = __builtin_amdgcn_mfma_f32_16x16x32_bf16(af[i][ks], bfr[j][ks], acc[i][j], 0, 0, 0);
        __builtin_amdgcn_s_setprio(0);
        __builtin_amdgcn_s_barrier();

        // ---- phase 3: read A half1 (reuse af regs); MFMA q10
#pragma unroll
        for (int i = 0; i < 4; i++) {
            const __bf16* r = pA + (arow + 64 + i * 16) * 64;
            af[i][0] = *(const bf16x8*)(r + off0);
            af[i][1] = *(const bf16x8*)(r + off1);
        }
        __builtin_amdgcn_s_barrier();
        __builtin_amdgcn_s_setprio(1);
#pragma unroll
        for (int ks = 0; ks < 2; ks++)
#pragma unroll
            for (int i = 0; i < 4; i++)
#pragma unroll
                for (int j = 0; j < 2; j++)
                    acc[4 + i][j] = __builtin_amdgcn_mfma_f32_16x16x32_bf16(af[i][ks], bfr[j][ks], acc[4 + i][j], 0, 0, 0);
        __builtin_amdgcn_s_setprio(0);
        __builtin_amdgcn_s_barrier();

        // ---- phase 4: MFMA q11; tile boundary (the ONLY vmcnt wait per tile)
        __builtin_amdgcn_s_setprio(1);
#pragma unroll
        for (int ks = 0; ks < 2; ks++)
#pragma unroll
            for (int i = 0; i < 4; i++)
#pragma unroll
                for (int j = 2; j < 4; j++)
                    acc[4 + i][j] = __builtin_amdgcn_mfma_f32_16x16x32_bf16(af[i][ks], bfr[j][ks], acc[4 + i][j], 0, 0, 0);
        __builtin_amdgcn_s_setprio(0);
        asm volatile("s_waitcnt vmcnt(0) lgkmcnt(0)" ::: "memory");
        __builtin_amdgcn_s_barrier();
    }

    // ---- epilogue
#pragma unroll
    for (int j = 0; j < 4; j++) {
        const int n = n0 + wn * 64 + j * 16 + lr;
        if (n < N) {
            const float bv = BIAS ? bias[n] : 0.f;
#pragma unroll
            for (int i = 0; i < 8; i++) {
#pragma unroll
                for (int r = 0; r < 4; r++) {
                    const int m = m0 + wm * 128 + i * 16 + lq * 4 + r;
                    float v = acc[i][j][r] + bv;
                    if (GELU) v = gelu_f(v);
                    if (OUTBF) ((__bf16*)Cout)[(size_t)m * ldc + n] = (__bf16)v;
                    else       ((float*)Cout)[(size_t)m * ldc + n] = v;
                }
            }
        }
    }
}

// ---------------------------------------------------------------- bf16 MFMA GEMM 128x128, BK=64, pipelined
// nT = N/128 tiles in n; grid = (M/128)*nT blocks (multiple of 8).
// XCD swizzle: each XCD owns grid/8 consecutive tiles, n-fastest -> A panels
// L2-resident per XCD.
template<bool BIAS, bool GELU, bool SKIP>
__global__ __launch_bounds__(256, 2) void mgemm128_k(
    const __bf16* __restrict__ A, int lda,
    const __bf16* __restrict__ Bt, int ldb,
    const float* __restrict__ bias,
    const float* __restrict__ skip, int ldskip,
    float* __restrict__ Cout, int ldc,
    int N, int Kp, int nT)                             // Kp multiple of 64
{
    __shared__ __bf16 sAB[32768];   // [A db0 |A db1 |B db0 |B db1] x 8192 elems
    const int tid = threadIdx.x;
    const int w = tid >> 6, lane = tid & 63;
    const int wm = w >> 1, wn = w & 1;
    const int lr = lane & 15, lq = lane >> 4;

    // bijective XCD swizzle
    const int bid = blockIdx.x;
    const int cpx = gridDim.x >> 3;
    const int swz = (bid & 7) * cpx + (bid >> 3);
    const int m0 = (swz / nT) * 128, n0 = (swz % nT) * 128;

    const int rr  = tid >> 3;
    const int csw = ((tid & 7) ^ (rr & 7)) << 3;
    const __bf16* gA[4]; const __bf16* gB[4];
#pragma unroll
    for (int c = 0; c < 4; c++) {
        gA[c] = A + (size_t)(m0 + c * 32 + rr) * lda + csw;
        gB[c] = Bt + (size_t)(n0 + c * 32 + rr) * ldb + csw;
    }
    __bf16* lA = sAB + (w << 9);            // + db*8192 + c*2048
    __bf16* lB = sAB + 16384 + (w << 9);

    const int off0 = (lq * 8) ^ ((lr & 7) << 3);
    const int off1 = off0 ^ 32;
    const int arow = wm * 64 + lr;
    const int brow = wn * 64 + lr;

    f32x4 zero = {0.f, 0.f, 0.f, 0.f};
    f32x4 acc[4][4];
#pragma unroll
    for (int i = 0; i < 4; i++)
#pragma unroll
        for (int j = 0; j < 4; j++) acc[i][j] = zero;

    // prologue: stage K-tile 0 -> db0
#pragma unroll
    for (int c = 0; c < 4; c++) {
        g2l16(gA[c], lA + c * 2048);
        g2l16(gB[c], lB + c * 2048);
    }
    asm volatile("s_waitcnt vmcnt(0)" ::: "memory");
    __builtin_amdgcn_s_barrier();

    const int NT = Kp >> 6;
    for (int kt = 0; kt < NT; ++kt) {
        const int cur = kt & 1;
        const __bf16* pA = sAB + cur * 8192;
        const __bf16* pB = sAB + 16384 + cur * 8192;
        bf16x8 af[4][2], bfr[4][2];

        // ---- phase 1: issue next-tile stage; read all A + B[0..1]; 16 MFMA (j=0,1)
        if (kt + 1 < NT) {
            const int ko = (kt + 1) << 6;
            __bf16* dA = lA + (cur ^ 1) * 8192;
            __bf16* dB = lB + (cur ^ 1) * 8192;
#pragma unroll
            for (int c = 0; c < 4; c++) {
                g2l16(gA[c] + ko, dA + c * 2048);
                g2l16(gB[c] + ko, dB + c * 2048);
            }
        }
#pragma unroll
        for (int i = 0; i < 4; i++) {
            const __bf16* r = pA + (arow + i * 16) * 64;
            af[i][0] = *(const bf16x8*)(r + off0);
            af[i][1] = *(const bf16x8*)(r + off1);
        }
#pragma unroll
        for (int j = 0; j < 2; j++) {
            const __bf16* r = pB + (brow + j * 16) * 64;
            bfr[j][0] = *(const bf16x8*)(r + off0);
            bfr[j][1] = *(const bf16x8*)(r + off1);
        }
        __builtin_amdgcn_s_barrier();
        __builtin_amdgcn_s_setprio(1);
#pragma unroll
        for (int ks = 0; ks < 2; ks++)
#pragma unroll
            for (int i = 0; i < 4; i++)
#pragma unroll
                for (int j = 0; j < 2; j++)
                    acc[i][j] = __builtin_amdgcn_mfma_f32_16x16x32_bf16(af[i][ks], bfr[j][ks], acc[i][j], 0, 0, 0);
        __builtin_amdgcn_s_setprio(0);
        __builtin_amdgcn_s_barrier();

        // ---- phase 2: read B[2..3]; 16 MFMA (j=2,3); tile boundary
#pragma unroll
        for (int j = 2; j < 4; j++) {
            const __bf16* r = pB + (brow + j * 16) * 64;
            bfr[j][0] = *(const bf16x8*)(r + off0);
            bfr[j][1] = *(const bf16x8*)(r + off1);
        }
        __builtin_amdgcn_s_barrier();
        __builtin_amdgcn_s_setprio(1);
#pragma unroll
        for (int ks = 0; ks < 2; ks++)
#pragma unroll
            for (int i = 0; i < 4; i++)
#pragma unroll
                for (int j = 2; j < 4; j++)
                    acc[i][j] = __builtin_amdgcn_mfma_f32_16x16x32_bf16(af[i][ks], bfr[j][ks], acc[i][j], 0, 0, 0);
        __builtin_amdgcn_s_setprio(0);
        asm volatile("s_waitcnt vmcnt(0) lgkmcnt(0)" ::: "memory");
        __builtin_amdgcn_s_barrier();
    }

    // ---- epilogue
#pragma unroll
    for (int j = 0; j < 4; j++) {
        const int n = n0 + wn * 64 + j * 16 + lr;
        if (n < N) {
            const float bv = BIAS ? bias[n] : 0.f;
#pragma unroll
            for (int i = 0; i < 4; i++) {
#pragma unroll
                for (int r = 0; r < 4; r++) {
                    const int m = m0 + wm * 64 + i * 16 + lq * 4 + r;
                    float v = acc[i][j][r] + bv;
                    if (GELU) v = gelu_f(v);
                    if (SKIP) v += skip[(size_t)m * ldskip + n];
                    Cout[(size_t)m * ldc + n] = v;
                }
            }
        }
    }
}

// ---------------------------------------------------------------- RoPE in-place(q) + Kb bf16 + q/k norms
__global__ __launch_bounds__(256) void rope_k(
    float* __restrict__ QKV, const float* __restrict__ curv,
    float* __restrict__ qt, float* __restrict__ kt,
    __bf16* __restrict__ Kb, __bf16* __restrict__ Obf)
{
    int row = blockIdx.x;              // b*T + t
    int b = row >> 11, t = row & (TT - 1);
    int wv = threadIdx.x >> 6, d = threadIdx.x & 63;
    int j = d & 31;
    float fr = (float)t * powf(10000.0f, -(float)(2 * j) / 64.0f);
    float cv = cosf(fr), sv = sinf(fr);
    float sgn = (d < 32) ? sv : -sv;
    for (int h = wv; h < HH; h += 4) {
        float Kh = expf(curv[h]);
        float* base = QKV + (size_t)row * 3072 + h * 64;
        float q = base[d], k = base[1024 + d];
        float qp = __shfl_xor(q, 32);
        float kp = __shfl_xor(k, 32);
        float qr = q * cv + qp * sgn;
        float kr = k * cv + kp * sgn;
        base[d] = qr;                         // q roped in place (fp32 for hi/lo split)
        size_t oidx = ((size_t)(b * HH + h) * TT + t);
        Kb[oidx * 64 + d] = (__bf16)kr;       // roped k, bf16 head-major
        float sq = qr * qr, sk = kr * kr;
#pragma unroll
        for (int o = 32; o; o >>= 1) {
            sq += __shfl_xor(sq, o);
            sk += __shfl_xor(sk, o);
        }
        if (d == 0) {
            qt[oidx] = sqrtf(Kh + sq);
            kt[oidx] = sqrtf(Kh + sk);
        }
    }
    if (threadIdx.x < 48) Obf[(size_t)row * 1088 + 1040 + threadIdx.x] = (__bf16)0.f;
}

// ---------------------------------------------------------------- V transpose -> Vtb bf16 [bh][d][t] + vt norms
__global__ __launch_bounds__(256) void vtrans_k(
    const float* __restrict__ QKV, const float* __restrict__ curv,
    __bf16* __restrict__ Vtb, float* __restrict__ vt)
{
    __shared__ float sT[64 * 65];
    int bh = blockIdx.y; int h = bh & (HH - 1); int b = bh >> 4;
    int t0 = blockIdx.x * 64;
    int tid = threadIdx.x, w = tid >> 6, lane = tid & 63;
    float Kh = expf(curv[h]);
    const float* vbase = QKV + (size_t)(b * TT + t0) * 3072 + 2048 + h * 64;
#pragma unroll 4
    for (int i = 0; i < 16; i++) {
        int tr = w * 16 + i;
        float v = vbase[(size_t)tr * 3072 + lane];
        sT[lane * 65 + tr] = v;
        float s = v * v;
#pragma unroll
        for (int o = 32; o; o >>= 1) s += __shfl_xor(s, o);
        if (lane == 0) vt[(size_t)bh * TT + t0 + tr] = sqrtf(Kh + s);
    }
    __syncthreads();
    int d = tid >> 2, seg = tid & 3;
    const float* r = &sT[d * 65 + seg * 16];
    bf16x8 o0, o1;
#pragma unroll
    for (int i = 0; i < 8; i++) { o0[i] = (__bf16)r[i]; o1[i] = (__bf16)r[8 + i]; }
    __bf16* dst = Vtb + ((size_t)bh * 64 + d) * TT + t0 + seg * 16;
    *(bf16x8*)dst = o0;
    *(bf16x8*)(dst + 8) = o1;
}

// ---------------------------------------------------------------- MFMA flash hyperbolic attention (v8)
// v7 + 512 threads / 128-row q-block (8 waves share one K/V staging + one
// barrier per tile -> 2x residency: 24 waves/CU) + setprio around MFMA.
__global__ __launch_bounds__(512, 4) void flash_k(
    const float* __restrict__ QKV,
    const __bf16* __restrict__ Kb, const __bf16* __restrict__ Vtb,
    const float* __restrict__ qt, const float* __restrict__ kt,
    const float* __restrict__ vt,
    const float* __restrict__ curv,
    __bf16* __restrict__ O)
{
    __shared__ __bf16 sK[2][4096];   // [buf][ksp][dgrp][s=64][8 d]
    __shared__ __bf16 sVt[2][4096];  // [buf][ksp][tgrp][d=64][8 t]
    __shared__ __bf16 sP[8 * 16 * 72];
    __shared__ float skt[2][64], svt[2][64];

    int bh = blockIdx.x; int h = bh & (HH - 1); int b = bh >> 4;
    int qti = 15 - (int)blockIdx.y;        // heavy blocks dispatch first
    int q0 = qti << 7;                     // 128-row q block
    int NJ = (qti << 1) + 2;
    float Kh = expf(curv[h]);
    float sqKh = sqrtf(Kh), msqK = -sqKh, invKh = 1.0f / Kh;
    const float* tok = QKV + (size_t)b * TT * 3072 + h * 64;  // roped q fp32
    const char* KbB = (const char*)Kb + (size_t)bh * TT * 128;
    const char* VtB = (const char*)Vtb + (size_t)bh * 64 * (TT * 2);
    const float* qtp = qt + (size_t)bh * TT;
    const float* ktp = kt + (size_t)bh * TT;
    const float* vtp = vt + (size_t)bh * TT;

    int tid = threadIdx.x;
    int w = tid >> 6, lane = tid & 63;
    int m = lane & 15, quad = lane >> 4;
    int wq = w & 3, half = w >> 2;         // staging role: d/t-group, k-half
    int myBase = q0 + 16 * w;              // all 8 waves share the same j-range
    __bf16* sPw = &sP[w * 16 * 72];

    // Q fragments (hi + lo bf16), A-layout: A[m][k=quad*8+j+32*ks]
    bf16x8 qhi[2], qlo[2];
    {
        const float* qrow = tok + (size_t)(myBase + m) * 3072;
#pragma unroll
        for (int ks = 0; ks < 2; ks++) {
            const float* s = qrow + quad * 8 + 32 * ks;
            float4 f0 = *(const float4*)s;
            float4 f1 = *(const float4*)(s + 4);
            float fa[8] = {f0.x, f0.y, f0.z, f0.w, f1.x, f1.y, f1.z, f1.w};
#pragma unroll
            for (int jj = 0; jj < 8; jj++) {
                __bf16 hv = (__bf16)fa[jj];
                qhi[ks][jj] = hv;
                qlo[ks][jj] = (__bf16)(fa[jj] - (float)hv);
            }
        }
    }
    float qtv[4]; int qg[4];
#pragma unroll
    for (int r = 0; r < 4; r++) { qg[r] = myBase + quad * 4 + r; qtv[r] = qtp[qg[r]]; }

    f32x4 zero = {0.f, 0.f, 0.f, 0.f};
    f32x4 accO[4];
#pragma unroll
    for (int nt = 0; nt < 4; nt++) accO[nt] = zero;
    float lsumr[4] = {}, o0r[4] = {};

    // per-wave staging dest bases (wave-uniform; HW adds lane*16)
    const int stoff = half * 4096 + wq * 1024;   // bytes

    // ---- prologue: stage tile 0 -> buf 0 (1 K + 1 V g2l16 per thread)
    g2l16(KbB + (size_t)lane * 128 + half * 64 + wq * 16, (char*)&sK[0][0] + stoff);
    g2l16(VtB + (size_t)lane * (TT * 2) + half * 64 + wq * 16, (char*)&sVt[0][0] + stoff);
    if (tid < 64) skt[0][tid] = ktp[tid];
    else if (tid < 128) svt[0][tid - 64] = vtp[tid - 64];
    __syncthreads();

    for (int j = 0; j < NJ; ++j) {
        int cur = j & 1;
        int sb = j << 6;
        // ---- issue next-tile stage EARLY (latency hides under compute) ----
        if (j + 1 < NJ) {
            int sb2 = sb + 64;
            g2l16(KbB + (size_t)(sb2 + lane) * 128 + half * 64 + wq * 16,
                  (char*)&sK[cur ^ 1][0] + stoff);
            g2l16(VtB + (size_t)lane * (TT * 2) + sb2 * 2 + half * 64 + wq * 16,
                  (char*)&sVt[cur ^ 1][0] + stoff);
            if (tid < 64) skt[cur ^ 1][tid] = ktp[sb2 + tid];
            else if (tid < 128) svt[cur ^ 1][tid - 64] = vtp[sb2 + tid - 64];
        }

        // ---- QK^T: S[16 x 64] ----
        f32x4 accS[4];
#pragma unroll
        for (int nt = 0; nt < 4; nt++) accS[nt] = zero;
        __builtin_amdgcn_s_setprio(1);
#pragma unroll
        for (int nt = 0; nt < 4; nt++) {
#pragma unroll
            for (int ksp = 0; ksp < 2; ksp++) {
                bf16x8 bk = *(const bf16x8*)&sK[cur][((ksp * 4 + quad) * 64 + nt * 16 + m) * 8];
                accS[nt] = __builtin_amdgcn_mfma_f32_16x16x32_bf16(qhi[ksp], bk, accS[nt], 0, 0, 0);
                accS[nt] = __builtin_amdgcn_mfma_f32_16x16x32_bf16(qlo[ksp], bk, accS[nt], 0, 0, 0);
            }
        }
        __builtin_amdgcn_s_setprio(0);
        // ---- score epilogue: hyperbolic logit -> p, raw transcendentals ----
#pragma unroll
        for (int nt = 0; nt < 4; nt++) {
            int col = nt * 16 + m;
            int sglob = sb + col;
            float ktv = skt[cur][col], vtv = svt[cur][col];
#pragma unroll
            for (int r = 0; r < 4; r++) {
                float dot = accS[nt][r];
                float rdiff = fmaf(qtv[r], ktv, -dot);          // qt*kt - q.k
                float ratio = fmaxf(rdiff * invKh, 1.0f + 1e-7f);
                float y = ratio + fsqrt_(fmaf(ratio, ratio, -1.0f));
                float pv = fexp2(msqK * flog2(y));              // exp(-sqrt(K)*acosh)
                float p = (sglob <= qg[r]) ? pv : 0.0f;
                lsumr[r] += p;
                o0r[r] = fmaf(p, vtv, o0r[r]);
                sPw[(quad * 4 + r) * 72 + col] = (__bf16)p;
            }
        }
        __asm__ volatile("s_waitcnt lgkmcnt(0)" ::: "memory");
        // ---- PV: O += P @ V ----
        __builtin_amdgcn_s_setprio(1);
#pragma unroll
        for (int ksp = 0; ksp < 2; ksp++) {
            bf16x8 aP = *(const bf16x8*)&sPw[m * 72 + ksp * 32 + quad * 8];
#pragma unroll
            for (int nt = 0; nt < 4; nt++) {
                bf16x8 bV = *(const bf16x8*)&sVt[cur][((ksp * 4 + quad) * 64 + nt * 16 + m) * 8];
                accO[nt] = __builtin_amdgcn_mfma_f32_16x16x32_bf16(aP, bV, accO[nt], 0, 0, 0);
            }
        }
        __builtin_amdgcn_s_setprio(0);
        __syncthreads();   // drains vmcnt+lgkm: next-tile staging complete, buf reuse safe
    }

    // ---- final: reduce lsum/o0 over the 16 col-lanes, normalize, write ----
#pragma unroll
    for (int r = 0; r < 4; r++) {
#pragma unroll
        for (int off = 1; off < 16; off <<= 1) {
            lsumr[r] += __shfl_xor(lsumr[r], off);
            o0r[r]   += __shfl_xor(o0r[r], off);
        }
    }
#pragma unroll
    for (int r = 0; r < 4; r++) {
        float inv = frcp_(lsumr[r]);
        float o0f = o0r[r] * inv;
        float ov[4]; float part = 0.f;
#pragma unroll
        for (int nt = 0; nt < 4; nt++) { float t = accO[nt][r] * inv; ov[nt] = t; part += t * t; }
        part += __shfl_xor(part, 1);
        part += __shfl_xor(part, 2);
        part += __shfl_xor(part, 4);
        part += __shfl_xor(part, 8);
        float scale = sqKh * frsq_(fmaxf(o0f * o0f - part, 1e-12f));
        size_t orow = (size_t)(b * TT + qg[r]) * 1088 + h * 65;
        if (m == 0) O[orow] = (__bf16)(o0f * scale);
#pragma unroll
        for (int nt = 0; nt < 4; nt++) O[orow + 1 + nt * 16 + m] = (__bf16)(ov[nt] * scale);
    }
}

// ---------------------------------------------------------------- launch
extern "C" void kernel_launch(void* const* d_in, const int* in_sizes, int n_in,
                              void* d_out, int out_size, void* d_ws, size_t ws_size,
                              hipStream_t stream) {
    const float* x    = (const float*)d_in[0];
    const float* bc   = (const float*)d_in[1];
    const float* mc   = (const float*)d_in[2];
    const float* ac   = (const float*)d_in[3];
    const float* w_qkv = (const float*)d_in[4];
    const float* w_ap  = (const float*)d_in[5];
    const float* b_ap  = (const float*)d_in[6];
    const float* w_me  = (const float*)d_in[7];
    const float* b_me  = (const float*)d_in[8];
    const float* w_ms  = (const float*)d_in[9];
    const float* b_ms  = (const float*)d_in[10];
    const float* lnw  = (const float*)d_in[11];
    const float* lnb  = (const float*)d_in[12];
    float* out = (float*)d_out;
    float* ws  = (float*)d_ws;

    // workspace (floats), total ~96.5 MB.
    float* R      = ws;
    float* qkvbuf = R;                             // M*3072 fp32 (dead after flash)
    float* X2     = R;                             // M*1024 fp32 (written step 5)
    __bf16* h_bf  = (__bf16*)(R + 4194304);        // M*4224 bf16 -> ends 12,845,056
    float* p      = R + 12845056;
    __bf16* ln_bf = (__bf16*)p;  p += 2228224;     // M*1088 bf16
    __bf16* o_bf  = (__bf16*)p;  p += 2228224;     // M*1088 bf16
    __bf16* qkvT  = (__bf16*)p;  p += 1671168;     // 3072*1088 bf16
    __bf16* apT   = (__bf16*)p;  p += 557056;      // 1024*1088 bf16
    float*  meT_f = p;           p += 2229856;     // 4099*1088 bf16 (after flash)
    float*  msT_f = p;           p += 2162688;     // 1024*4224 bf16 (after flash)
    float* Qt = p;               p += 2 * HH * TT;
    float* Kt = p;               p += 2 * HH * TT;
    float* Vt = p;
    __bf16* meT = (__bf16*)meT_f;
    __bf16* msT = (__bf16*)msT_f;
    __bf16* Kb  = (__bf16*)meT_f;   // 32*2048*64 bf16 <= meT slot; dead before wt_k(meT)
    __bf16* Vtb = (__bf16*)msT_f;   // same size      <= msT slot; dead before wt_k(msT)

    // 0. weight transposes needed before flash (zero-filled past K)
    wt_k<<<dim3(34, 96),  256, 0, stream>>>(w_qkv, 1025, 3072, qkvT, 1088);
    wt_k<<<dim3(34, 32),  256, 0, stream>>>(w_ap,  1040, 1024, apT,  1088);

    // 1. ln1 = block_norm(project(x)) -> bf16 (stride 1088, zero pad)
    block_norm_bf_k<<<MM, 256, 0, stream>>>(x, 1024, ln_bf, 1088, lnw, lnb, bc);
    // 2. qkv = ln1 @ w_qkv -> fp32 (M,3072)   [128^2, 768 blocks, 2/CU co-resident]
    mgemm128_k<false, false, false><<<dim3(768), 256, 0, stream>>>(
        ln_bf, 1088, qkvT, 1088, nullptr, nullptr, 0, qkvbuf, 3072, 3072, 1088, 24);
    // 3a. RoPE (q in place fp32, Kb bf16) + q/k norms + o_bf pad (cols 1040..1087)
    rope_k<<<MM, 256, 0, stream>>>(qkvbuf, ac, Qt, Kt, Kb, o_bf);
    // 3b. V transpose -> Vtb bf16 + v norms
    vtrans_k<<<dim3(32, 32), 256, 0, stream>>>(qkvbuf, ac, Vtb, Vt);
    // 4. MFMA flash attention -> o_t bf16 (M,1088)   [512 thr, 128-row q-blocks]
    flash_k<<<dim3(2 * HH, 16), 512, 0, stream>>>(qkvbuf, Kb, Vtb, Qt, Kt, Vt, ac, o_bf);
    // 0b. remaining weight transposes (into the slots Kb/Vtb just vacated)
    wt_k<<<dim3(34, 129), 256, 0, stream>>>(w_me,  1025, 4099, meT, 1088);
    wt_k<<<dim3(132, 32), 256, 0, stream>>>(w_ms,  4100, 1024, msT, 4224);
    // 5. lx2[...,1:] = x + o_t @ w_attn_proj + b -> X2 fp32   [128^2 pipelined]
    mgemm128_k<true, false, true><<<dim3(256), 256, 0, stream>>>(
        o_bf, 1088, apT, 1088, b_ap, x, 1024, X2, 1024, 1024, 1088, 8);
    // 6. ln2 = block_norm(lx2) -> bf16
    block_norm_bf_k<<<MM, 256, 0, stream>>>(X2, 1024, ln_bf, 1088, lnw, lnb, bc);
    // 7. h[1..4096] = gelu(ln2 @ w_mlp_expand + b) -> bf16   [256^2, XCD-chunked, exact 16x16]
    mgemm256_k<true, true, true><<<dim3(16, 16), 512, 0, stream>>>(
        ln_bf, 1088, meT, 1088, 4099, b_me, (void*)(h_bf + 1), 4224, 4099, 1088);
    // 8. h cols 4097..4099 (ragged tail vs meT rows 4096..4098) + x0 + pad
    row_x0_tail_k<<<MM, 256, 0, stream>>>(h_bf, ln_bf, meT, b_me, mc);
    // 9. out[...,1:] = lx2[...,1:] + h @ w_mlp_shrink + b   [128^2 pipelined]
    mgemm128_k<true, false, true><<<dim3(256), 256, 0, stream>>>(
        h_bf, 4224, msT, 4224, b_ms, X2, 1024, out + 1, 1025, 1024, 4224, 8);
    // 10. out[...,0]
    row_x0_k<<<MM, 256, 0, stream>>>(out, 1025, 1024, bc);
}

// Round 7
// 457.353 us; speedup vs baseline: 1.0130x; 1.0130x over previous
//
#include <hip/hip_runtime.h>
#include <math.h>

// Problem constants: B=2, T=2048, E=1024, H=16, D=64; M = B*T = 4096
#define MM   4096
#define TT   2048
#define HH   16

typedef __bf16 bf16x8 __attribute__((ext_vector_type(8)));
typedef float f32x4 __attribute__((ext_vector_type(4)));

// async global->LDS, 16B per lane; LDS dest = wave-uniform base + lane*16
__device__ __forceinline__ void g2l16(const void* g, void* l) {
    __builtin_amdgcn_global_load_lds(
        (__attribute__((address_space(1))) void*)g,
        (__attribute__((address_space(3))) void*)l, 16, 0, 0);
}

// ---- raw transcendentals (guarded; libm fallback). Without -ffast-math the
// libm versions lower to multi-instruction OCML guard sequences — 3-4x cost.
#if __has_builtin(__builtin_amdgcn_exp2f)
__device__ __forceinline__ float fexp2(float x) { return __builtin_amdgcn_exp2f(x); }
#else
__device__ __forceinline__ float fexp2(float x) { return exp2f(x); }
#endif
#if __has_builtin(__builtin_amdgcn_logf)
__device__ __forceinline__ float flog2(float x) { return __builtin_amdgcn_logf(x); }
#else
__device__ __forceinline__ float flog2(float x) { return log2f(x); }
#endif
#if __has_builtin(__builtin_amdgcn_sqrtf)
__device__ __forceinline__ float fsqrt_(float x) { return __builtin_amdgcn_sqrtf(x); }
#else
__device__ __forceinline__ float fsqrt_(float x) { return sqrtf(x); }
#endif
#if __has_builtin(__builtin_amdgcn_rcpf)
__device__ __forceinline__ float frcp_(float x) { return __builtin_amdgcn_rcpf(x); }
#else
__device__ __forceinline__ float frcp_(float x) { return 1.0f / x; }
#endif
#if __has_builtin(__builtin_amdgcn_rsqf)
__device__ __forceinline__ float frsq_(float x) { return __builtin_amdgcn_rsqf(x); }
#else
__device__ __forceinline__ float frsq_(float x) { return rsqrtf(x); }
#endif

// fast GELU (tanh form, abs err ~1e-3; ref tolerance 0.25 and downstream
// weights are 0.02-scale -> negligible). Replaces libm erff (~35 VALU ops).
__device__ __forceinline__ float gelu_f(float x) {
    float u = 0.7978845608028654f * fmaf(0.044715f * x, x * x, x);
    u = fminf(fmaxf(u, -15.f), 15.f);
    float t = fexp2(-2.885390081777927f * u);     // e^{-2u}
    return 0.5f * x * (1.f + (1.f - t) * frcp_(1.f + t));
}

// ---------------------------------------------------------------- reductions
__device__ __forceinline__ float blockSum256(float v, volatile float* sb) {
    int lane = threadIdx.x & 63, w = threadIdx.x >> 6;
#pragma unroll
    for (int o = 32; o; o >>= 1) v += __shfl_xor(v, o);
    if (lane == 0) sb[w] = v;
    __syncthreads();
    v = sb[0] + sb[1] + sb[2] + sb[3];
    __syncthreads();
    return v;
}

// ---------------------------------------------------------------- block_norm -> bf16 (ldo-wide, zero pad)
__global__ __launch_bounds__(256) void block_norm_bf_k(
    const float* __restrict__ in, int ld,
    __bf16* __restrict__ out, int ldo,
    const float* __restrict__ lw, const float* __restrict__ lb,
    const float* __restrict__ curv)
{
    int row = blockIdx.x;
    const float* x = in + (size_t)row * ld;
    __bf16* o = out + (size_t)row * ldo;
    __shared__ float sb[4];
    int tid = threadIdx.x;
    float v[4]; float s1 = 0.f, s2 = 0.f;
#pragma unroll
    for (int r = 0; r < 4; r++) {
        float t = x[tid + 256 * r];
        v[r] = t; s1 += t; s2 += t * t;
    }
    s1 = blockSum256(s1, sb);
    s2 = blockSum256(s2, sb);
    float mean = s1 * (1.f / 1024.f);
    float var  = s2 * (1.f / 1024.f) - mean * mean;
    float rs = rsqrtf(var + 1e-5f);
    float y[4]; float ssq = 0.f;
#pragma unroll
    for (int r = 0; r < 4; r++) {
        int i = tid + 256 * r;
        float t = (v[r] - mean) * rs * lw[i] + lb[i];
        y[r] = t; ssq += t * t;
    }
    ssq = blockSum256(ssq, sb);
#pragma unroll
    for (int r = 0; r < 4; r++) o[1 + tid + 256 * r] = (__bf16)y[r];
    if (tid == 0) o[0] = (__bf16)sqrtf(expf(*curv) + ssq);
    if (tid < ldo - 1025) o[1025 + tid] = (__bf16)0.f;   // zero pad cols 1025..ldo-1
}

// ---------------------------------------------------------------- row x0 (fp32, final output)
__global__ __launch_bounds__(256) void row_x0_k(
    float* __restrict__ buf, int stride, int n, const float* __restrict__ curv)
{
    int row = blockIdx.x;
    float* base = buf + (size_t)row * stride;
    __shared__ float sb[4];
    float s = 0.f;
    for (int i = threadIdx.x; i < n; i += 256) { float t = base[1 + i]; s += t * t; }
    s = blockSum256(s, sb);
    if (threadIdx.x == 0) base[0] = sqrtf(expf(*curv) + s);
}

// ---------------------------------------------------------------- h tail (3 ragged cols) + x0 + pad (stride 4224)
__global__ __launch_bounds__(256) void row_x0_tail_k(
    __bf16* __restrict__ h,
    const __bf16* __restrict__ ln,      // ln2, stride 1088 (zero-padded past 1025)
    const __bf16* __restrict__ Bt,      // meT, stride 1088
    const float* __restrict__ bias,     // b_me (4099)
    const float* __restrict__ curv)
{
    int row = blockIdx.x;
    __bf16* base = h + (size_t)row * 4224;
    const __bf16* lnr = ln + (size_t)row * 1088;
    const __bf16* B0 = Bt + (size_t)4096 * 1088;
    const __bf16* B1 = Bt + (size_t)4097 * 1088;
    const __bf16* B2 = Bt + (size_t)4098 * 1088;
    __shared__ float sb[4];
    float d0 = 0.f, d1 = 0.f, d2 = 0.f;
    for (int i = threadIdx.x; i < 1088; i += 256) {
        float a = (float)lnr[i];
        d0 += a * (float)B0[i];
        d1 += a * (float)B1[i];
        d2 += a * (float)B2[i];
    }
    d0 = blockSum256(d0, sb);
    d1 = blockSum256(d1, sb);
    d2 = blockSum256(d2, sb);
    float t3[3] = {d0 + bias[4096], d1 + bias[4097], d2 + bias[4098]};
    float ssq_t = 0.f;
#pragma unroll
    for (int j = 0; j < 3; j++) {
        float v = gelu_f(t3[j]);
        t3[j] = v; ssq_t += v * v;
    }
    if (threadIdx.x == 0) {
        base[1 + 4096] = (__bf16)t3[0];
        base[1 + 4097] = (__bf16)t3[1];
        base[1 + 4098] = (__bf16)t3[2];
    }
    float s = 0.f;
    for (int i = threadIdx.x; i < 4096; i += 256) { float t = (float)base[1 + i]; s += t * t; }
    s = blockSum256(s, sb) + ssq_t;
    if (threadIdx.x == 0) base[0] = (__bf16)sqrtf(expf(*curv) + s);
    if (threadIdx.x < 124) base[4100 + threadIdx.x] = (__bf16)0.f;  // zero pad 4100..4223
}

// ---------------------------------------------------------------- weight convert + transpose
__global__ __launch_bounds__(256) void wt_k(
    const float* __restrict__ W, int K, int N,
    __bf16* __restrict__ Wt, int Kp)
{
    __shared__ float s[32][33];
    int tx = threadIdx.x & 31, ty = threadIdx.x >> 5;    // 32 x 8
    int k0 = blockIdx.x * 32, n0 = blockIdx.y * 32;
#pragma unroll
    for (int r = 0; r < 4; r++) {
        int k = k0 + ty + 8 * r, n = n0 + tx;
        s[ty + 8 * r][tx] = (k < K && n < N) ? W[(size_t)k * N + n] : 0.f;
    }
    __syncthreads();
#pragma unroll
    for (int r = 0; r < 4; r++) {
        int n = n0 + ty + 8 * r, k = k0 + tx;
        if (n < N) Wt[(size_t)n * Kp + k] = (__bf16)s[tx][ty + 8 * r];
    }
}

// ---------------------------------------------------------------- bf16 MFMA GEMM 128x128, BK=32, TRIPLE-buffered
// counted-vmcnt pipeline (T4): stage(kt+2) issued each iter; boundary waits
// vmcnt(4) (stage kt+1 landed, kt+2 in flight) — loads span barriers, never
// drained to 0 in steady state. LDS 48 KB (3 x (8KB A + 8KB B)) -> 3 blk/CU.
// Swizzle: 16B chunk ^= (row>>1)&3, both-sides (pre-swizzled global source,
// swizzled ds_read). Read pattern = 8 start-banks x 8 lanes x 16B = one full
// 32-bank sweep per phase -> ~0 conflicts. Bijective XCD swizzle (grid%8==0).
template<bool BIAS, bool GELU, bool SKIP, bool OUTBF>
__global__ __launch_bounds__(256, 3) void mgemm128_k(
    const __bf16* __restrict__ A, int lda,
    const __bf16* __restrict__ Bt, int ldb,
    const float* __restrict__ bias,
    const float* __restrict__ skip, int ldskip,
    void* __restrict__ Cout, int ldc,
    int N, int Kp, int nT)                             // Kp multiple of 32, NT>=3
{
    __shared__ __bf16 sAB[24576];   // A: 3 x 4096 elems | B: 12288 + 3 x 4096
    const int tid = threadIdx.x;
    const int w = tid >> 6, lane = tid & 63;
    const int wm = w >> 1, wn = w & 1;
    const int lr = lane & 15, lq = lane >> 4;

    const int bid = blockIdx.x;
    const int cpx = gridDim.x >> 3;
    const int swz = (bid & 7) * cpx + (bid >> 3);
    const int m0 = (swz / nT) * 128, n0 = (swz % nT) * 128;

    // staging: load c (c=0,1) covers rows [c*64, c*64+64); thread t -> row
    // c*64 + (t>>2), 16B chunk (t&3); source chunk pre-swizzled by (row>>1)&3.
    const int rr  = tid >> 2;                       // 0..63
    const int csw = ((tid & 3) ^ ((rr >> 1) & 3)) << 3;   // elems
    const __bf16* gA[2]; const __bf16* gB[2];
#pragma unroll
    for (int c = 0; c < 2; c++) {
        gA[c] = A + (size_t)(m0 + c * 64 + rr) * lda + csw;
        gB[c] = Bt + (size_t)(n0 + c * 64 + rr) * ldb + csw;
    }
    const int wst = w * 512;                        // wave slice within a load-chunk

    // read: frag row stride 32 elems (64B); chunk = lq ^ ((lr>>1)&3)
    const int off = (lq ^ ((lr >> 1) & 3)) << 3;
    const int arow = wm * 64 + lr;
    const int brow = wn * 64 + lr;

    f32x4 zero = {0.f, 0.f, 0.f, 0.f};
    f32x4 acc[4][4];
#pragma unroll
    for (int i = 0; i < 4; i++)
#pragma unroll
        for (int j = 0; j < 4; j++) acc[i][j] = zero;

    const int NT = Kp >> 5;
    // prologue: stage kt=0 -> buf0, kt=1 -> buf1 (4 loads each)
#pragma unroll
    for (int c = 0; c < 2; c++) {
        g2l16(gA[c], sAB + c * 2048 + wst);
        g2l16(gB[c], sAB + 12288 + c * 2048 + wst);
    }
#pragma unroll
    for (int c = 0; c < 2; c++) {
        g2l16(gA[c] + 32, sAB + 4096 + c * 2048 + wst);
        g2l16(gB[c] + 32, sAB + 12288 + 4096 + c * 2048 + wst);
    }
    asm volatile("s_waitcnt vmcnt(4)" ::: "memory");   // stage0 landed
    __builtin_amdgcn_s_barrier();

    int cur = 0;
    for (int kt = 0; kt < NT; ++kt) {
        // ---- issue stage(kt+2) -> buf (cur+2)%3 (its last readers finished iter kt-1)
        if (kt + 2 < NT) {
            const int sbuf = (cur == 0) ? 2 : (cur - 1);      // (cur+2)%3
            const int ko = (kt + 2) << 5;
#pragma unroll
            for (int c = 0; c < 2; c++) {
                g2l16(gA[c] + ko, sAB + sbuf * 4096 + c * 2048 + wst);
                g2l16(gB[c] + ko, sAB + 12288 + sbuf * 4096 + c * 2048 + wst);
            }
        }
        const __bf16* pA = sAB + cur * 4096;
        const __bf16* pB = sAB + 12288 + cur * 4096;
        bf16x8 af[4], bf[4];
#pragma unroll
        for (int i = 0; i < 4; i++) af[i] = *(const bf16x8*)&pA[(arow + i * 16) * 32 + off];
#pragma unroll
        for (int j = 0; j < 4; j++) bf[j] = *(const bf16x8*)&pB[(brow + j * 16) * 32 + off];
        __builtin_amdgcn_s_setprio(1);
#pragma unroll
        for (int i = 0; i < 4; i++)
#pragma unroll
            for (int j = 0; j < 4; j++)
                acc[i][j] = __builtin_amdgcn_mfma_f32_16x16x32_bf16(af[i], bf[j], acc[i][j], 0, 0, 0);
        __builtin_amdgcn_s_setprio(0);
        // ---- boundary: counted wait — stage(kt+1) landed, stage(kt+2) stays in flight
        if (kt + 2 < NT) { asm volatile("s_waitcnt vmcnt(4)" ::: "memory"); }
        else             { asm volatile("s_waitcnt vmcnt(0) lgkmcnt(0)" ::: "memory"); }
        __builtin_amdgcn_s_barrier();
        cur = (cur == 2) ? 0 : (cur + 1);
    }

    // ---- epilogue
#pragma unroll
    for (int j = 0; j < 4; j++) {
        const int n = n0 + wn * 64 + j * 16 + lr;
        if (n < N) {
            const float bv = BIAS ? bias[n] : 0.f;
#pragma unroll
            for (int i = 0; i < 4; i++) {
#pragma unroll
                for (int r = 0; r < 4; r++) {
                    const int m = m0 + wm * 64 + i * 16 + lq * 4 + r;
                    float v = acc[i][j][r] + bv;
                    if (GELU) v = gelu_f(v);
                    if (SKIP) v += skip[(size_t)m * ldskip + n];
                    if (OUTBF) ((__bf16*)Cout)[(size_t)m * ldc + n] = (__bf16)v;
                    else       ((float*)Cout)[(size_t)m * ldc + n] = v;
                }
            }
        }
    }
}

// ---------------------------------------------------------------- RoPE in-place(q) + Kb bf16 + q/k norms
__global__ __launch_bounds__(256) void rope_k(
    float* __restrict__ QKV, const float* __restrict__ curv,
    float* __restrict__ qt, float* __restrict__ kt,
    __bf16* __restrict__ Kb, __bf16* __restrict__ Obf)
{
    int row = blockIdx.x;              // b*T + t
    int b = row >> 11, t = row & (TT - 1);
    int wv = threadIdx.x >> 6, d = threadIdx.x & 63;
    int j = d & 31;
    float fr = (float)t * powf(10000.0f, -(float)(2 * j) / 64.0f);
    float cv = cosf(fr), sv = sinf(fr);
    float sgn = (d < 32) ? sv : -sv;
    for (int h = wv; h < HH; h += 4) {
        float Kh = expf(curv[h]);
        float* base = QKV + (size_t)row * 3072 + h * 64;
        float q = base[d], k = base[1024 + d];
        float qp = __shfl_xor(q, 32);
        float kp = __shfl_xor(k, 32);
        float qr = q * cv + qp * sgn;
        float kr = k * cv + kp * sgn;
        base[d] = qr;                         // q roped in place (fp32 for hi/lo split)
        size_t oidx = ((size_t)(b * HH + h) * TT + t);
        Kb[oidx * 64 + d] = (__bf16)kr;       // roped k, bf16 head-major
        float sq = qr * qr, sk = kr * kr;
#pragma unroll
        for (int o = 32; o; o >>= 1) {
            sq += __shfl_xor(sq, o);
            sk += __shfl_xor(sk, o);
        }
        if (d == 0) {
            qt[oidx] = sqrtf(Kh + sq);
            kt[oidx] = sqrtf(Kh + sk);
        }
    }
    if (threadIdx.x < 48) Obf[(size_t)row * 1088 + 1040 + threadIdx.x] = (__bf16)0.f;
}

// ---------------------------------------------------------------- V transpose -> Vtb bf16 [bh][d][t] + vt norms
__global__ __launch_bounds__(256) void vtrans_k(
    const float* __restrict__ QKV, const float* __restrict__ curv,
    __bf16* __restrict__ Vtb, float* __restrict__ vt)
{
    __shared__ float sT[64 * 65];
    int bh = blockIdx.y; int h = bh & (HH - 1); int b = bh >> 4;
    int t0 = blockIdx.x * 64;
    int tid = threadIdx.x, w = tid >> 6, lane = tid & 63;
    float Kh = expf(curv[h]);
    const float* vbase = QKV + (size_t)(b * TT + t0) * 3072 + 2048 + h * 64;
#pragma unroll 4
    for (int i = 0; i < 16; i++) {
        int tr = w * 16 + i;
        float v = vbase[(size_t)tr * 3072 + lane];
        sT[lane * 65 + tr] = v;
        float s = v * v;
#pragma unroll
        for (int o = 32; o; o >>= 1) s += __shfl_xor(s, o);
        if (lane == 0) vt[(size_t)bh * TT + t0 + tr] = sqrtf(Kh + s);
    }
    __syncthreads();
    int d = tid >> 2, seg = tid & 3;
    const float* r = &sT[d * 65 + seg * 16];
    bf16x8 o0, o1;
#pragma unroll
    for (int i = 0; i < 8; i++) { o0[i] = (__bf16)r[i]; o1[i] = (__bf16)r[8 + i]; }
    __bf16* dst = Vtb + ((size_t)bh * 64 + d) * TT + t0 + seg * 16;
    *(bf16x8*)dst = o0;
    *(bf16x8*)(dst + 8) = o1;
}

// ---------------------------------------------------------------- MFMA flash hyperbolic attention (v7 = R5, proven 70us)
__global__ __launch_bounds__(256, 3) void flash_k(
    const float* __restrict__ QKV,
    const __bf16* __restrict__ Kb, const __bf16* __restrict__ Vtb,
    const float* __restrict__ qt, const float* __restrict__ kt,
    const float* __restrict__ vt,
    const float* __restrict__ curv,
    __bf16* __restrict__ O)
{
    __shared__ __bf16 sK[2][4096];   // [buf][dgrp4][s=64][8 d]
    __shared__ __bf16 sVt[2][4096];  // [buf][tgrp4][d=64][8 t]
    __shared__ __bf16 sP[4 * 16 * 72];
    __shared__ float skt[2][64], svt[2][64];

    int bh = blockIdx.x; int h = bh & (HH - 1); int b = bh >> 4;
    int qti = 31 - (int)blockIdx.y;        // heavy blocks dispatch first
    int q0 = qti << 6;
    int NJ = qti + 1;
    float Kh = expf(curv[h]);
    float sqKh = sqrtf(Kh), msqK = -sqKh, invKh = 1.0f / Kh;
    const float* tok = QKV + (size_t)b * TT * 3072 + h * 64;  // roped q fp32
    const char* KbB = (const char*)Kb + (size_t)bh * TT * 128;
    const char* VtB = (const char*)Vtb + (size_t)bh * 64 * (TT * 2);
    const float* qtp = qt + (size_t)bh * TT;
    const float* ktp = kt + (size_t)bh * TT;
    const float* vtp = vt + (size_t)bh * TT;

    int tid = threadIdx.x;
    int w = tid >> 6, lane = tid & 63;
    int m = lane & 15, quad = lane >> 4;
    int myBase = q0 + 16 * w;              // all 4 waves share the same j-range
    __bf16* sPw = &sP[w * 16 * 72];

    // Q fragments (hi + lo bf16), A-layout: A[m][k=quad*8+j+32*ks]
    bf16x8 qhi[2], qlo[2];
    {
        const float* qrow = tok + (size_t)(myBase + m) * 3072;
#pragma unroll
        for (int ks = 0; ks < 2; ks++) {
            const float* s = qrow + quad * 8 + 32 * ks;
            float4 f0 = *(const float4*)s;
            float4 f1 = *(const float4*)(s + 4);
            float fa[8] = {f0.x, f0.y, f0.z, f0.w, f1.x, f1.y, f1.z, f1.w};
#pragma unroll
            for (int jj = 0; jj < 8; jj++) {
                __bf16 hv = (__bf16)fa[jj];
                qhi[ks][jj] = hv;
                qlo[ks][jj] = (__bf16)(fa[jj] - (float)hv);
            }
        }
    }
    float qtv[4]; int qg[4];
#pragma unroll
    for (int r = 0; r < 4; r++) { qg[r] = myBase + quad * 4 + r; qtv[r] = qtp[qg[r]]; }

    f32x4 zero = {0.f, 0.f, 0.f, 0.f};
    f32x4 accO[4];
#pragma unroll
    for (int nt = 0; nt < 4; nt++) accO[nt] = zero;
    float lsumr[4] = {}, o0r[4] = {};

    // ---- prologue: stage tile 0 -> buf 0
    {
        const char* kg = KbB + (size_t)lane * 128 + w * 16;
        char* sKb = (char*)&sK[0][0] + w * 1024;
        g2l16(kg,      sKb);
        g2l16(kg + 64, sKb + 4096);
        const char* vg = VtB + (size_t)lane * (TT * 2) + w * 16;
        char* sVb = (char*)&sVt[0][0] + w * 1024;
        g2l16(vg,      sVb);
        g2l16(vg + 64, sVb + 4096);
    }
    if (tid < 64) skt[0][tid] = ktp[tid];
    else if (tid < 128) svt[0][tid - 64] = vtp[tid - 64];
    __syncthreads();

    for (int j = 0; j < NJ; ++j) {
        int cur = j & 1;
        int sb = j << 6;
        // ---- issue next-tile stage EARLY (latency hides under compute) ----
        if (j + 1 < NJ) {
            int sb2 = sb + 64;
            const char* kg = KbB + (size_t)(sb2 + lane) * 128 + w * 16;
            char* sKb = (char*)&sK[cur ^ 1][0] + w * 1024;
            g2l16(kg,      sKb);
            g2l16(kg + 64, sKb + 4096);
            const char* vg = VtB + (size_t)lane * (TT * 2) + sb2 * 2 + w * 16;
            char* sVb = (char*)&sVt[cur ^ 1][0] + w * 1024;
            g2l16(vg,      sVb);
            g2l16(vg + 64, sVb + 4096);
            if (tid < 64) skt[cur ^ 1][tid] = ktp[sb2 + tid];
            else if (tid < 128) svt[cur ^ 1][tid - 64] = vtp[sb2 + tid - 64];
        }

        // ---- QK^T: S[16 x 64] ----
        f32x4 accS[4];
#pragma unroll
        for (int nt = 0; nt < 4; nt++) accS[nt] = zero;
#pragma unroll
        for (int nt = 0; nt < 4; nt++) {
#pragma unroll
            for (int ksp = 0; ksp < 2; ksp++) {
                bf16x8 bk = *(const bf16x8*)&sK[cur][((ksp * 4 + quad) * 64 + nt * 16 + m) * 8];
                accS[nt] = __builtin_amdgcn_mfma_f32_16x16x32_bf16(qhi[ksp], bk, accS[nt], 0, 0, 0);
                accS[nt] = __builtin_amdgcn_mfma_f32_16x16x32_bf16(qlo[ksp], bk, accS[nt], 0, 0, 0);
            }
        }
        // ---- score epilogue: hyperbolic logit -> p, raw transcendentals ----
#pragma unroll
        for (int nt = 0; nt < 4; nt++) {
            int col = nt * 16 + m;
            int sglob = sb + col;
            float ktv = skt[cur][col], vtv = svt[cur][col];
#pragma unroll
            for (int r = 0; r < 4; r++) {
                float dot = accS[nt][r];
                float rdiff = fmaf(qtv[r], ktv, -dot);          // qt*kt - q.k
                float ratio = fmaxf(rdiff * invKh, 1.0f + 1e-7f);
                float y = ratio + fsqrt_(fmaf(ratio, ratio, -1.0f));
                float pv = fexp2(msqK * flog2(y));              // exp(-sqrt(K)*acosh)
                float p = (sglob <= qg[r]) ? pv : 0.0f;
                lsumr[r] += p;
                o0r[r] = fmaf(p, vtv, o0r[r]);
                sPw[(quad * 4 + r) * 72 + col] = (__bf16)p;
            }
        }
        __asm__ volatile("s_waitcnt lgkmcnt(0)" ::: "memory");
        // ---- PV: O += P @ V ----
#pragma unroll
        for (int ksp = 0; ksp < 2; ksp++) {
            bf16x8 aP = *(const bf16x8*)&sPw[m * 72 + ksp * 32 + quad * 8];
#pragma unroll
            for (int nt = 0; nt < 4; nt++) {
                bf16x8 bV = *(const bf16x8*)&sVt[cur][((ksp * 4 + quad) * 64 + nt * 16 + m) * 8];
                accO[nt] = __builtin_amdgcn_mfma_f32_16x16x32_bf16(aP, bV, accO[nt], 0, 0, 0);
            }
        }
        __syncthreads();   // drains vmcnt+lgkm: next-tile staging complete, buf reuse safe
    }

    // ---- final: reduce lsum/o0 over the 16 col-lanes, normalize, write ----
#pragma unroll
    for (int r = 0; r < 4; r++) {
#pragma unroll
        for (int off = 1; off < 16; off <<= 1) {
            lsumr[r] += __shfl_xor(lsumr[r], off);
            o0r[r]   += __shfl_xor(o0r[r], off);
        }
    }
#pragma unroll
    for (int r = 0; r < 4; r++) {
        float inv = frcp_(lsumr[r]);
        float o0f = o0r[r] * inv;
        float ov[4]; float part = 0.f;
#pragma unroll
        for (int nt = 0; nt < 4; nt++) { float t = accO[nt][r] * inv; ov[nt] = t; part += t * t; }
        part += __shfl_xor(part, 1);
        part += __shfl_xor(part, 2);
        part += __shfl_xor(part, 4);
        part += __shfl_xor(part, 8);
        float scale = sqKh * frsq_(fmaxf(o0f * o0f - part, 1e-12f));
        size_t orow = (size_t)(b * TT + qg[r]) * 1088 + h * 65;
        if (m == 0) O[orow] = (__bf16)(o0f * scale);
#pragma unroll
        for (int nt = 0; nt < 4; nt++) O[orow + 1 + nt * 16 + m] = (__bf16)(ov[nt] * scale);
    }
}

// ---------------------------------------------------------------- launch
extern "C" void kernel_launch(void* const* d_in, const int* in_sizes, int n_in,
                              void* d_out, int out_size, void* d_ws, size_t ws_size,
                              hipStream_t stream) {
    const float* x    = (const float*)d_in[0];
    const float* bc   = (const float*)d_in[1];
    const float* mc   = (const float*)d_in[2];
    const float* ac   = (const float*)d_in[3];
    const float* w_qkv = (const float*)d_in[4];
    const float* w_ap  = (const float*)d_in[5];
    const float* b_ap  = (const float*)d_in[6];
    const float* w_me  = (const float*)d_in[7];
    const float* b_me  = (const float*)d_in[8];
    const float* w_ms  = (const float*)d_in[9];
    const float* b_ms  = (const float*)d_in[10];
    const float* lnw  = (const float*)d_in[11];
    const float* lnb  = (const float*)d_in[12];
    float* out = (float*)d_out;
    float* ws  = (float*)d_ws;

    // workspace (floats), total ~96.5 MB.
    float* R      = ws;
    float* qkvbuf = R;                             // M*3072 fp32 (dead after flash)
    float* X2     = R;                             // M*1024 fp32 (written step 5)
    __bf16* h_bf  = (__bf16*)(R + 4194304);        // M*4224 bf16 -> ends 12,845,056
    float* p      = R + 12845056;
    __bf16* ln_bf = (__bf16*)p;  p += 2228224;     // M*1088 bf16
    __bf16* o_bf  = (__bf16*)p;  p += 2228224;     // M*1088 bf16
    __bf16* qkvT  = (__bf16*)p;  p += 1671168;     // 3072*1088 bf16
    __bf16* apT   = (__bf16*)p;  p += 557056;      // 1024*1088 bf16
    float*  meT_f = p;           p += 2229856;     // 4099*1088 bf16 (after flash)
    float*  msT_f = p;           p += 2162688;     // 1024*4224 bf16 (after flash)
    float* Qt = p;               p += 2 * HH * TT;
    float* Kt = p;               p += 2 * HH * TT;
    float* Vt = p;
    __bf16* meT = (__bf16*)meT_f;
    __bf16* msT = (__bf16*)msT_f;
    __bf16* Kb  = (__bf16*)meT_f;   // 32*2048*64 bf16 <= meT slot; dead before wt_k(meT)
    __bf16* Vtb = (__bf16*)msT_f;   // same size      <= msT slot; dead before wt_k(msT)

    // 0. weight transposes needed before flash (zero-filled past K)
    wt_k<<<dim3(34, 96),  256, 0, stream>>>(w_qkv, 1025, 3072, qkvT, 1088);
    wt_k<<<dim3(34, 32),  256, 0, stream>>>(w_ap,  1040, 1024, apT,  1088);

    // 1. ln1 = block_norm(project(x)) -> bf16 (stride 1088, zero pad)
    block_norm_bf_k<<<MM, 256, 0, stream>>>(x, 1024, ln_bf, 1088, lnw, lnb, bc);
    // 2. qkv = ln1 @ w_qkv -> fp32 (M,3072)   [128^2 triple-buffer, 768 blocks, 3/CU]
    mgemm128_k<false, false, false, false><<<dim3(768), 256, 0, stream>>>(
        ln_bf, 1088, qkvT, 1088, nullptr, nullptr, 0, qkvbuf, 3072, 3072, 1088, 24);
    // 3a. RoPE (q in place fp32, Kb bf16) + q/k norms + o_bf pad (cols 1040..1087)
    rope_k<<<MM, 256, 0, stream>>>(qkvbuf, ac, Qt, Kt, Kb, o_bf);
    // 3b. V transpose -> Vtb bf16 + v norms
    vtrans_k<<<dim3(32, 32), 256, 0, stream>>>(qkvbuf, ac, Vtb, Vt);
    // 4. MFMA flash attention -> o_t bf16 (M,1088)   [R5-proven 256 thr, 1024 blocks]
    flash_k<<<dim3(2 * HH, 32), 256, 0, stream>>>(qkvbuf, Kb, Vtb, Qt, Kt, Vt, ac, o_bf);
    // 0b. remaining weight transposes (into the slots Kb/Vtb just vacated)
    wt_k<<<dim3(34, 129), 256, 0, stream>>>(w_me,  1025, 4099, meT, 1088);
    wt_k<<<dim3(132, 32), 256, 0, stream>>>(w_ms,  4100, 1024, msT, 4224);
    // 5. lx2[...,1:] = x + o_t @ w_attn_proj + b -> X2 fp32
    mgemm128_k<true, false, true, false><<<dim3(256), 256, 0, stream>>>(
        o_bf, 1088, apT, 1088, b_ap, x, 1024, X2, 1024, 1024, 1088, 8);
    // 6. ln2 = block_norm(lx2) -> bf16
    block_norm_bf_k<<<MM, 256, 0, stream>>>(X2, 1024, ln_bf, 1088, lnw, lnb, bc);
    // 7. h[1..4096] = gelu(ln2 @ w_mlp_expand + b) -> bf16   [128^2 triple-buffer, 1024 blocks]
    mgemm128_k<true, true, false, true><<<dim3(1024), 256, 0, stream>>>(
        ln_bf, 1088, meT, 1088, b_me, nullptr, 0, (void*)(h_bf + 1), 4224, 4096, 1088, 32);
    // 8. h cols 4097..4099 (ragged tail vs meT rows 4096..4098) + x0 + pad
    row_x0_tail_k<<<MM, 256, 0, stream>>>(h_bf, ln_bf, meT, b_me, mc);
    // 9. out[...,1:] = lx2[...,1:] + h @ w_mlp_shrink + b
    mgemm128_k<true, false, true, false><<<dim3(256), 256, 0, stream>>>(
        h_bf, 4224, msT, 4224, b_ms, X2, 1024, (void*)(out + 1), 1025, 1024, 4224, 8);
    // 10. out[...,0]
    row_x0_k<<<MM, 256, 0, stream>>>(out, 1025, 1024, bc);
}

// Round 8
// 447.654 us; speedup vs baseline: 1.0349x; 1.0217x over previous
//
#include <hip/hip_runtime.h>
#include <math.h>

// Problem constants: B=2, T=2048, E=1024, H=16, D=64; M = B*T = 4096
#define MM   4096
#define TT   2048
#define HH   16

typedef __bf16 bf16x8 __attribute__((ext_vector_type(8)));
typedef float f32x4 __attribute__((ext_vector_type(4)));

// async global->LDS, 16B per lane; LDS dest = wave-uniform base + lane*16
__device__ __forceinline__ void g2l16(const void* g, void* l) {
    __builtin_amdgcn_global_load_lds(
        (__attribute__((address_space(1))) void*)g,
        (__attribute__((address_space(3))) void*)l, 16, 0, 0);
}

// ---- raw transcendentals (guarded; libm fallback). Without -ffast-math the
// libm versions lower to multi-instruction OCML guard sequences — 3-4x cost.
#if __has_builtin(__builtin_amdgcn_exp2f)
__device__ __forceinline__ float fexp2(float x) { return __builtin_amdgcn_exp2f(x); }
#else
__device__ __forceinline__ float fexp2(float x) { return exp2f(x); }
#endif
#if __has_builtin(__builtin_amdgcn_logf)
__device__ __forceinline__ float flog2(float x) { return __builtin_amdgcn_logf(x); }
#else
__device__ __forceinline__ float flog2(float x) { return log2f(x); }
#endif
#if __has_builtin(__builtin_amdgcn_sqrtf)
__device__ __forceinline__ float fsqrt_(float x) { return __builtin_amdgcn_sqrtf(x); }
#else
__device__ __forceinline__ float fsqrt_(float x) { return sqrtf(x); }
#endif
#if __has_builtin(__builtin_amdgcn_rcpf)
__device__ __forceinline__ float frcp_(float x) { return __builtin_amdgcn_rcpf(x); }
#else
__device__ __forceinline__ float frcp_(float x) { return 1.0f / x; }
#endif
#if __has_builtin(__builtin_amdgcn_rsqf)
__device__ __forceinline__ float frsq_(float x) { return __builtin_amdgcn_rsqf(x); }
#else
__device__ __forceinline__ float frsq_(float x) { return rsqrtf(x); }
#endif

// fast GELU (tanh form, abs err ~1e-3; ref tolerance 0.25 and downstream
// weights are 0.02-scale -> negligible). Replaces libm erff (~35 VALU ops).
__device__ __forceinline__ float gelu_f(float x) {
    float u = 0.7978845608028654f * fmaf(0.044715f * x, x * x, x);
    u = fminf(fmaxf(u, -15.f), 15.f);
    float t = fexp2(-2.885390081777927f * u);     // e^{-2u}
    return 0.5f * x * (1.f + (1.f - t) * frcp_(1.f + t));
}

// ---------------------------------------------------------------- reductions
__device__ __forceinline__ float blockSum256(float v, volatile float* sb) {
    int lane = threadIdx.x & 63, w = threadIdx.x >> 6;
#pragma unroll
    for (int o = 32; o; o >>= 1) v += __shfl_xor(v, o);
    if (lane == 0) sb[w] = v;
    __syncthreads();
    v = sb[0] + sb[1] + sb[2] + sb[3];
    __syncthreads();
    return v;
}

// ---------------------------------------------------------------- block_norm -> bf16 (ldo-wide, zero pad)
__global__ __launch_bounds__(256) void block_norm_bf_k(
    const float* __restrict__ in, int ld,
    __bf16* __restrict__ out, int ldo,
    const float* __restrict__ lw, const float* __restrict__ lb,
    const float* __restrict__ curv)
{
    int row = blockIdx.x;
    const float* x = in + (size_t)row * ld;
    __bf16* o = out + (size_t)row * ldo;
    __shared__ float sb[4];
    int tid = threadIdx.x;
    float v[4]; float s1 = 0.f, s2 = 0.f;
#pragma unroll
    for (int r = 0; r < 4; r++) {
        float t = x[tid + 256 * r];
        v[r] = t; s1 += t; s2 += t * t;
    }
    s1 = blockSum256(s1, sb);
    s2 = blockSum256(s2, sb);
    float mean = s1 * (1.f / 1024.f);
    float var  = s2 * (1.f / 1024.f) - mean * mean;
    float rs = rsqrtf(var + 1e-5f);
    float y[4]; float ssq = 0.f;
#pragma unroll
    for (int r = 0; r < 4; r++) {
        int i = tid + 256 * r;
        float t = (v[r] - mean) * rs * lw[i] + lb[i];
        y[r] = t; ssq += t * t;
    }
    ssq = blockSum256(ssq, sb);
#pragma unroll
    for (int r = 0; r < 4; r++) o[1 + tid + 256 * r] = (__bf16)y[r];
    if (tid == 0) o[0] = (__bf16)sqrtf(expf(*curv) + ssq);
    if (tid < ldo - 1025) o[1025 + tid] = (__bf16)0.f;   // zero pad cols 1025..ldo-1
}

// ---------------------------------------------------------------- final out: copy aligned P -> out[...,1:], x0 col
__global__ __launch_bounds__(256) void out_final_k(
    float* __restrict__ out, const float* __restrict__ P,
    const float* __restrict__ curv)
{
    int row = blockIdx.x;
    const float* p = P + (size_t)row * 1024;
    float* o = out + (size_t)row * 1025;
    __shared__ float sb[4];
    int tid = threadIdx.x;
    float v[4]; float s = 0.f;
#pragma unroll
    for (int r = 0; r < 4; r++) { float t = p[tid + 256 * r]; v[r] = t; s += t * t; }
    s = blockSum256(s, sb);
#pragma unroll
    for (int r = 0; r < 4; r++) o[1 + tid + 256 * r] = v[r];
    if (tid == 0) o[0] = sqrtf(expf(*curv) + s);
}

// ---------------------------------------------------------------- h tail (3 ragged cols) + x0 + pad (stride 4224)
// h layout (permuted, aligned): cols 0..4095 = gelu(h_1..h_4096) [from expand
// GEMM at aligned offset 0], cols 4096..4098 = gelu(h_4097..4099) [here],
// col 4099 = x0, cols 4100..4223 = 0. msT rows rotated to match.
__global__ __launch_bounds__(256) void row_x0_tail_k(
    __bf16* __restrict__ h,
    const __bf16* __restrict__ ln,      // ln2, stride 1088 (zero-padded past 1025)
    const __bf16* __restrict__ Bt,      // meT, stride 1088
    const float* __restrict__ bias,     // b_me (4099)
    const float* __restrict__ curv)
{
    int row = blockIdx.x;
    __bf16* base = h + (size_t)row * 4224;
    const __bf16* lnr = ln + (size_t)row * 1088;
    const __bf16* B0 = Bt + (size_t)4096 * 1088;
    const __bf16* B1 = Bt + (size_t)4097 * 1088;
    const __bf16* B2 = Bt + (size_t)4098 * 1088;
    __shared__ float sb[4];
    float d0 = 0.f, d1 = 0.f, d2 = 0.f;
    for (int i = threadIdx.x; i < 1088; i += 256) {
        float a = (float)lnr[i];
        d0 += a * (float)B0[i];
        d1 += a * (float)B1[i];
        d2 += a * (float)B2[i];
    }
    d0 = blockSum256(d0, sb);
    d1 = blockSum256(d1, sb);
    d2 = blockSum256(d2, sb);
    float t3[3] = {d0 + bias[4096], d1 + bias[4097], d2 + bias[4098]};
    float ssq_t = 0.f;
#pragma unroll
    for (int j = 0; j < 3; j++) {
        float v = gelu_f(t3[j]);
        t3[j] = v; ssq_t += v * v;
    }
    if (threadIdx.x == 0) {
        base[4096] = (__bf16)t3[0];
        base[4097] = (__bf16)t3[1];
        base[4098] = (__bf16)t3[2];
    }
    float s = 0.f;
    for (int i = threadIdx.x; i < 4096; i += 256) { float t = (float)base[i]; s += t * t; }
    s = blockSum256(s, sb) + ssq_t;
    if (threadIdx.x == 0) base[4099] = (__bf16)sqrtf(expf(*curv) + s);   // x0 col
    if (threadIdx.x < 124) base[4100 + threadIdx.x] = (__bf16)0.f;       // zero pad
}

// ---------------------------------------------------------------- weight convert + transpose
// ROT: destination k index rotated by -1 mod K (k=0 -> K-1) — used for msT so
// the augmented x0 row lands at col K-1 and h rows at 0..K-2 (aligned h).
template<bool ROT>
__global__ __launch_bounds__(256) void wt_k(
    const float* __restrict__ W, int K, int N,
    __bf16* __restrict__ Wt, int Kp)
{
    __shared__ float s[32][33];
    int tx = threadIdx.x & 31, ty = threadIdx.x >> 5;    // 32 x 8
    int k0 = blockIdx.x * 32, n0 = blockIdx.y * 32;
#pragma unroll
    for (int r = 0; r < 4; r++) {
        int k = k0 + ty + 8 * r, n = n0 + tx;
        s[ty + 8 * r][tx] = (k < K && n < N) ? W[(size_t)k * N + n] : 0.f;
    }
    __syncthreads();
#pragma unroll
    for (int r = 0; r < 4; r++) {
        int n = n0 + ty + 8 * r, k = k0 + tx;
        int kd = (ROT && k < K) ? ((k == 0) ? (K - 1) : (k - 1)) : k;
        if (n < N) Wt[(size_t)n * Kp + kd] = (__bf16)s[tx][ty + 8 * r];
    }
}

// ---------------------------------------------------------------- bf16 MFMA GEMM 128x128, BK=32, TRIPLE-buffered
// counted-vmcnt pipeline (T4) + 2D XCD chunking: the 8 XCDs tile the output
// as 4 m-groups x 2 n-groups, so each XCD's working set = A/4-ish + B/2
// (fits 4MB L2; the old 1D chunking put ALL of B in every XCD -> refetch).
// Requires Mtiles%4==0, nT%2==0, grid%8==0.
template<bool BIAS, bool GELU, bool SKIP, bool OUTBF>
__global__ __launch_bounds__(256, 3) void mgemm128_k(
    const __bf16* __restrict__ A, int lda,
    const __bf16* __restrict__ Bt, int ldb,
    const float* __restrict__ bias,
    const float* __restrict__ skip, int ldskip,
    void* __restrict__ Cout, int ldc,
    int N, int Kp, int nT)                             // Kp multiple of 32, NT>=3
{
    __shared__ __bf16 sAB[24576];   // A: 3 x 4096 elems | B: 12288 + 3 x 4096
    const int tid = threadIdx.x;
    const int w = tid >> 6, lane = tid & 63;
    const int wm = w >> 1, wn = w & 1;
    const int lr = lane & 15, lq = lane >> 4;

    // 2D XCD chunking (bijective): xcd -> (xm = xcd>>1, xn = xcd&1)
    const int bid = blockIdx.x;
    const int xcd = bid & 7, loc = bid >> 3;
    const int nH = nT >> 1;                         // n-tiles per XCD n-group
    const int mH = (gridDim.x >> 3) / nH;           // m-tiles per XCD m-group
    const int mt = (xcd >> 1) * mH + loc / nH;
    const int nt = (xcd & 1) * nH + loc % nH;
    const int m0 = mt * 128, n0 = nt * 128;

    // staging: load c (c=0,1) covers rows [c*64, c*64+64); thread t -> row
    // c*64 + (t>>2), 16B chunk (t&3); source chunk pre-swizzled by (row>>1)&3.
    const int rr  = tid >> 2;                       // 0..63
    const int csw = ((tid & 3) ^ ((rr >> 1) & 3)) << 3;   // elems
    const __bf16* gA[2]; const __bf16* gB[2];
#pragma unroll
    for (int c = 0; c < 2; c++) {
        gA[c] = A + (size_t)(m0 + c * 64 + rr) * lda + csw;
        gB[c] = Bt + (size_t)(n0 + c * 64 + rr) * ldb + csw;
    }
    const int wst = w * 512;                        // wave slice within a load-chunk

    // read: frag row stride 32 elems (64B); chunk = lq ^ ((lr>>1)&3)
    const int off = (lq ^ ((lr >> 1) & 3)) << 3;
    const int arow = wm * 64 + lr;
    const int brow = wn * 64 + lr;

    f32x4 zero = {0.f, 0.f, 0.f, 0.f};
    f32x4 acc[4][4];
#pragma unroll
    for (int i = 0; i < 4; i++)
#pragma unroll
        for (int j = 0; j < 4; j++) acc[i][j] = zero;

    const int NT = Kp >> 5;
    // prologue: stage kt=0 -> buf0, kt=1 -> buf1 (4 loads each)
#pragma unroll
    for (int c = 0; c < 2; c++) {
        g2l16(gA[c], sAB + c * 2048 + wst);
        g2l16(gB[c], sAB + 12288 + c * 2048 + wst);
    }
#pragma unroll
    for (int c = 0; c < 2; c++) {
        g2l16(gA[c] + 32, sAB + 4096 + c * 2048 + wst);
        g2l16(gB[c] + 32, sAB + 12288 + 4096 + c * 2048 + wst);
    }
    asm volatile("s_waitcnt vmcnt(4)" ::: "memory");   // stage0 landed
    __builtin_amdgcn_s_barrier();

    int cur = 0;
    for (int kt = 0; kt < NT; ++kt) {
        // ---- issue stage(kt+2) -> buf (cur+2)%3 (its last readers finished iter kt-1)
        if (kt + 2 < NT) {
            const int sbuf = (cur == 0) ? 2 : (cur - 1);      // (cur+2)%3
            const int ko = (kt + 2) << 5;
#pragma unroll
            for (int c = 0; c < 2; c++) {
                g2l16(gA[c] + ko, sAB + sbuf * 4096 + c * 2048 + wst);
                g2l16(gB[c] + ko, sAB + 12288 + sbuf * 4096 + c * 2048 + wst);
            }
        }
        const __bf16* pA = sAB + cur * 4096;
        const __bf16* pB = sAB + 12288 + cur * 4096;
        bf16x8 af[4], bf[4];
#pragma unroll
        for (int i = 0; i < 4; i++) af[i] = *(const bf16x8*)&pA[(arow + i * 16) * 32 + off];
#pragma unroll
        for (int j = 0; j < 4; j++) bf[j] = *(const bf16x8*)&pB[(brow + j * 16) * 32 + off];
        __builtin_amdgcn_s_setprio(1);
#pragma unroll
        for (int i = 0; i < 4; i++)
#pragma unroll
            for (int j = 0; j < 4; j++)
                acc[i][j] = __builtin_amdgcn_mfma_f32_16x16x32_bf16(af[i], bf[j], acc[i][j], 0, 0, 0);
        __builtin_amdgcn_s_setprio(0);
        // ---- boundary: counted wait — stage(kt+1) landed, stage(kt+2) stays in flight
        if (kt + 2 < NT) { asm volatile("s_waitcnt vmcnt(4)" ::: "memory"); }
        else             { asm volatile("s_waitcnt vmcnt(0) lgkmcnt(0)" ::: "memory"); }
        __builtin_amdgcn_s_barrier();
        cur = (cur == 2) ? 0 : (cur + 1);
    }

    // ---- epilogue
#pragma unroll
    for (int j = 0; j < 4; j++) {
        const int n = n0 + wn * 64 + j * 16 + lr;
        if (n < N) {
            const float bv = BIAS ? bias[n] : 0.f;
#pragma unroll
            for (int i = 0; i < 4; i++) {
#pragma unroll
                for (int r = 0; r < 4; r++) {
                    const int m = m0 + wm * 64 + i * 16 + lq * 4 + r;
                    float v = acc[i][j][r] + bv;
                    if (GELU) v = gelu_f(v);
                    if (SKIP) v += skip[(size_t)m * ldskip + n];
                    if (OUTBF) ((__bf16*)Cout)[(size_t)m * ldc + n] = (__bf16)v;
                    else       ((float*)Cout)[(size_t)m * ldc + n] = v;
                }
            }
        }
    }
}

// ---------------------------------------------------------------- RoPE in-place(q) + Kb bf16 + q/k norms
__global__ __launch_bounds__(256) void rope_k(
    float* __restrict__ QKV, const float* __restrict__ curv,
    float* __restrict__ qt, float* __restrict__ kt,
    __bf16* __restrict__ Kb, __bf16* __restrict__ Obf)
{
    int row = blockIdx.x;              // b*T + t
    int b = row >> 11, t = row & (TT - 1);
    int wv = threadIdx.x >> 6, d = threadIdx.x & 63;
    int j = d & 31;
    float fr = (float)t * powf(10000.0f, -(float)(2 * j) / 64.0f);
    float cv = cosf(fr), sv = sinf(fr);
    float sgn = (d < 32) ? sv : -sv;
    for (int h = wv; h < HH; h += 4) {
        float Kh = expf(curv[h]);
        float* base = QKV + (size_t)row * 3072 + h * 64;
        float q = base[d], k = base[1024 + d];
        float qp = __shfl_xor(q, 32);
        float kp = __shfl_xor(k, 32);
        float qr = q * cv + qp * sgn;
        float kr = k * cv + kp * sgn;
        base[d] = qr;                         // q roped in place (fp32 for hi/lo split)
        size_t oidx = ((size_t)(b * HH + h) * TT + t);
        Kb[oidx * 64 + d] = (__bf16)kr;       // roped k, bf16 head-major
        float sq = qr * qr, sk = kr * kr;
#pragma unroll
        for (int o = 32; o; o >>= 1) {
            sq += __shfl_xor(sq, o);
            sk += __shfl_xor(sk, o);
        }
        if (d == 0) {
            qt[oidx] = sqrtf(Kh + sq);
            kt[oidx] = sqrtf(Kh + sk);
        }
    }
    if (threadIdx.x < 48) Obf[(size_t)row * 1088 + 1040 + threadIdx.x] = (__bf16)0.f;
}

// ---------------------------------------------------------------- V transpose -> Vtb bf16 [bh][d][t] + vt norms
__global__ __launch_bounds__(256) void vtrans_k(
    const float* __restrict__ QKV, const float* __restrict__ curv,
    __bf16* __restrict__ Vtb, float* __restrict__ vt)
{
    __shared__ float sT[64 * 65];
    int bh = blockIdx.y; int h = bh & (HH - 1); int b = bh >> 4;
    int t0 = blockIdx.x * 64;
    int tid = threadIdx.x, w = tid >> 6, lane = tid & 63;
    float Kh = expf(curv[h]);
    const float* vbase = QKV + (size_t)(b * TT + t0) * 3072 + 2048 + h * 64;
#pragma unroll 4
    for (int i = 0; i < 16; i++) {
        int tr = w * 16 + i;
        float v = vbase[(size_t)tr * 3072 + lane];
        sT[lane * 65 + tr] = v;
        float s = v * v;
#pragma unroll
        for (int o = 32; o; o >>= 1) s += __shfl_xor(s, o);
        if (lane == 0) vt[(size_t)bh * TT + t0 + tr] = sqrtf(Kh + s);
    }
    __syncthreads();
    int d = tid >> 2, seg = tid & 3;
    const float* r = &sT[d * 65 + seg * 16];
    bf16x8 o0, o1;
#pragma unroll
    for (int i = 0; i < 8; i++) { o0[i] = (__bf16)r[i]; o1[i] = (__bf16)r[8 + i]; }
    __bf16* dst = Vtb + ((size_t)bh * 64 + d) * TT + t0 + seg * 16;
    *(bf16x8*)dst = o0;
    *(bf16x8*)(dst + 8) = o1;
}

// ---------------------------------------------------------------- MFMA flash hyperbolic attention (v7 = R5, proven)
__global__ __launch_bounds__(256, 3) void flash_k(
    const float* __restrict__ QKV,
    const __bf16* __restrict__ Kb, const __bf16* __restrict__ Vtb,
    const float* __restrict__ qt, const float* __restrict__ kt,
    const float* __restrict__ vt,
    const float* __restrict__ curv,
    __bf16* __restrict__ O)
{
    __shared__ __bf16 sK[2][4096];   // [buf][dgrp4][s=64][8 d]
    __shared__ __bf16 sVt[2][4096];  // [buf][tgrp4][d=64][8 t]
    __shared__ __bf16 sP[4 * 16 * 72];
    __shared__ float skt[2][64], svt[2][64];

    int bh = blockIdx.x; int h = bh & (HH - 1); int b = bh >> 4;
    int qti = 31 - (int)blockIdx.y;        // heavy blocks dispatch first
    int q0 = qti << 6;
    int NJ = qti + 1;
    float Kh = expf(curv[h]);
    float sqKh = sqrtf(Kh), msqK = -sqKh, invKh = 1.0f / Kh;
    const float* tok = QKV + (size_t)b * TT * 3072 + h * 64;  // roped q fp32
    const char* KbB = (const char*)Kb + (size_t)bh * TT * 128;
    const char* VtB = (const char*)Vtb + (size_t)bh * 64 * (TT * 2);
    const float* qtp = qt + (size_t)bh * TT;
    const float* ktp = kt + (size_t)bh * TT;
    const float* vtp = vt + (size_t)bh * TT;

    int tid = threadIdx.x;
    int w = tid >> 6, lane = tid & 63;
    int m = lane & 15, quad = lane >> 4;
    int myBase = q0 + 16 * w;              // all 4 waves share the same j-range
    __bf16* sPw = &sP[w * 16 * 72];

    // Q fragments (hi + lo bf16), A-layout: A[m][k=quad*8+j+32*ks]
    bf16x8 qhi[2], qlo[2];
    {
        const float* qrow = tok + (size_t)(myBase + m) * 3072;
#pragma unroll
        for (int ks = 0; ks < 2; ks++) {
            const float* s = qrow + quad * 8 + 32 * ks;
            float4 f0 = *(const float4*)s;
            float4 f1 = *(const float4*)(s + 4);
            float fa[8] = {f0.x, f0.y, f0.z, f0.w, f1.x, f1.y, f1.z, f1.w};
#pragma unroll
            for (int jj = 0; jj < 8; jj++) {
                __bf16 hv = (__bf16)fa[jj];
                qhi[ks][jj] = hv;
                qlo[ks][jj] = (__bf16)(fa[jj] - (float)hv);
            }
        }
    }
    float qtv[4]; int qg[4];
#pragma unroll
    for (int r = 0; r < 4; r++) { qg[r] = myBase + quad * 4 + r; qtv[r] = qtp[qg[r]]; }

    f32x4 zero = {0.f, 0.f, 0.f, 0.f};
    f32x4 accO[4];
#pragma unroll
    for (int nt = 0; nt < 4; nt++) accO[nt] = zero;
    float lsumr[4] = {}, o0r[4] = {};

    // ---- prologue: stage tile 0 -> buf 0
    {
        const char* kg = KbB + (size_t)lane * 128 + w * 16;
        char* sKb = (char*)&sK[0][0] + w * 1024;
        g2l16(kg,      sKb);
        g2l16(kg + 64, sKb + 4096);
        const char* vg = VtB + (size_t)lane * (TT * 2) + w * 16;
        char* sVb = (char*)&sVt[0][0] + w * 1024;
        g2l16(vg,      sVb);
        g2l16(vg + 64, sVb + 4096);
    }
    if (tid < 64) skt[0][tid] = ktp[tid];
    else if (tid < 128) svt[0][tid - 64] = vtp[tid - 64];
    __syncthreads();

    for (int j = 0; j < NJ; ++j) {
        int cur = j & 1;
        int sb = j << 6;
        // ---- issue next-tile stage EARLY (latency hides under compute) ----
        if (j + 1 < NJ) {
            int sb2 = sb + 64;
            const char* kg = KbB + (size_t)(sb2 + lane) * 128 + w * 16;
            char* sKb = (char*)&sK[cur ^ 1][0] + w * 1024;
            g2l16(kg,      sKb);
            g2l16(kg + 64, sKb + 4096);
            const char* vg = VtB + (size_t)lane * (TT * 2) + sb2 * 2 + w * 16;
            char* sVb = (char*)&sVt[cur ^ 1][0] + w * 1024;
            g2l16(vg,      sVb);
            g2l16(vg + 64, sVb + 4096);
            if (tid < 64) skt[cur ^ 1][tid] = ktp[sb2 + tid];
            else if (tid < 128) svt[cur ^ 1][tid - 64] = vtp[sb2 + tid - 64];
        }

        // ---- QK^T: S[16 x 64] ----
        f32x4 accS[4];
#pragma unroll
        for (int nt = 0; nt < 4; nt++) accS[nt] = zero;
#pragma unroll
        for (int nt = 0; nt < 4; nt++) {
#pragma unroll
            for (int ksp = 0; ksp < 2; ksp++) {
                bf16x8 bk = *(const bf16x8*)&sK[cur][((ksp * 4 + quad) * 64 + nt * 16 + m) * 8];
                accS[nt] = __builtin_amdgcn_mfma_f32_16x16x32_bf16(qhi[ksp], bk, accS[nt], 0, 0, 0);
                accS[nt] = __builtin_amdgcn_mfma_f32_16x16x32_bf16(qlo[ksp], bk, accS[nt], 0, 0, 0);
            }
        }
        // ---- score epilogue: hyperbolic logit -> p, raw transcendentals ----
#pragma unroll
        for (int nt = 0; nt < 4; nt++) {
            int col = nt * 16 + m;
            int sglob = sb + col;
            float ktv = skt[cur][col], vtv = svt[cur][col];
#pragma unroll
            for (int r = 0; r < 4; r++) {
                float dot = accS[nt][r];
                float rdiff = fmaf(qtv[r], ktv, -dot);          // qt*kt - q.k
                float ratio = fmaxf(rdiff * invKh, 1.0f + 1e-7f);
                float y = ratio + fsqrt_(fmaf(ratio, ratio, -1.0f));
                float pv = fexp2(msqK * flog2(y));              // exp(-sqrt(K)*acosh)
                float p = (sglob <= qg[r]) ? pv : 0.0f;
                lsumr[r] += p;
                o0r[r] = fmaf(p, vtv, o0r[r]);
                sPw[(quad * 4 + r) * 72 + col] = (__bf16)p;
            }
        }
        __asm__ volatile("s_waitcnt lgkmcnt(0)" ::: "memory");
        // ---- PV: O += P @ V ----
#pragma unroll
        for (int ksp = 0; ksp < 2; ksp++) {
            bf16x8 aP = *(const bf16x8*)&sPw[m * 72 + ksp * 32 + quad * 8];
#pragma unroll
            for (int nt = 0; nt < 4; nt++) {
                bf16x8 bV = *(const bf16x8*)&sVt[cur][((ksp * 4 + quad) * 64 + nt * 16 + m) * 8];
                accO[nt] = __builtin_amdgcn_mfma_f32_16x16x32_bf16(aP, bV, accO[nt], 0, 0, 0);
            }
        }
        __syncthreads();   // drains vmcnt+lgkm: next-tile staging complete, buf reuse safe
    }

    // ---- final: reduce lsum/o0 over the 16 col-lanes, normalize, write ----
#pragma unroll
    for (int r = 0; r < 4; r++) {
#pragma unroll
        for (int off = 1; off < 16; off <<= 1) {
            lsumr[r] += __shfl_xor(lsumr[r], off);
            o0r[r]   += __shfl_xor(o0r[r], off);
        }
    }
#pragma unroll
    for (int r = 0; r < 4; r++) {
        float inv = frcp_(lsumr[r]);
        float o0f = o0r[r] * inv;
        float ov[4]; float part = 0.f;
#pragma unroll
        for (int nt = 0; nt < 4; nt++) { float t = accO[nt][r] * inv; ov[nt] = t; part += t * t; }
        part += __shfl_xor(part, 1);
        part += __shfl_xor(part, 2);
        part += __shfl_xor(part, 4);
        part += __shfl_xor(part, 8);
        float scale = sqKh * frsq_(fmaxf(o0f * o0f - part, 1e-12f));
        size_t orow = (size_t)(b * TT + qg[r]) * 1088 + h * 65;
        if (m == 0) O[orow] = (__bf16)(o0f * scale);
#pragma unroll
        for (int nt = 0; nt < 4; nt++) O[orow + 1 + nt * 16 + m] = (__bf16)(ov[nt] * scale);
    }
}

// ---------------------------------------------------------------- launch
extern "C" void kernel_launch(void* const* d_in, const int* in_sizes, int n_in,
                              void* d_out, int out_size, void* d_ws, size_t ws_size,
                              hipStream_t stream) {
    const float* x    = (const float*)d_in[0];
    const float* bc   = (const float*)d_in[1];
    const float* mc   = (const float*)d_in[2];
    const float* ac   = (const float*)d_in[3];
    const float* w_qkv = (const float*)d_in[4];
    const float* w_ap  = (const float*)d_in[5];
    const float* b_ap  = (const float*)d_in[6];
    const float* w_me  = (const float*)d_in[7];
    const float* b_me  = (const float*)d_in[8];
    const float* w_ms  = (const float*)d_in[9];
    const float* b_ms  = (const float*)d_in[10];
    const float* lnw  = (const float*)d_in[11];
    const float* lnb  = (const float*)d_in[12];
    float* out = (float*)d_out;
    float* ws  = (float*)d_ws;

    // workspace (floats), total ~96.5 MB.
    float* R      = ws;
    float* qkvbuf = R;                             // M*3072 fp32 (dead after flash)
    float* X2     = R;                             // M*1024 fp32 (written step 5)
    __bf16* h_bf  = (__bf16*)(R + 4194304);        // M*4224 bf16 -> ends 12,845,056
    float* p      = R + 12845056;
    __bf16* ln_bf = (__bf16*)p;  p += 2228224;     // M*1088 bf16 (dead after step 8)
    __bf16* o_bf  = (__bf16*)p;  p += 2228224;     // M*1088 bf16 (dead after step 5)
    __bf16* qkvT  = (__bf16*)p;  p += 1671168;     // 3072*1088 bf16
    __bf16* apT   = (__bf16*)p;  p += 557056;      // 1024*1088 bf16
    float*  meT_f = p;           p += 2229856;     // 4099*1088 bf16 (after flash)
    float*  msT_f = p;           p += 2162688;     // 1024*4224 bf16 (after flash)
    float* Qt = p;               p += 2 * HH * TT;
    float* Kt = p;               p += 2 * HH * TT;
    float* Vt = p;
    __bf16* meT = (__bf16*)meT_f;
    __bf16* msT = (__bf16*)msT_f;
    __bf16* Kb  = (__bf16*)meT_f;   // 32*2048*64 bf16 <= meT slot; dead before wt_k(meT)
    __bf16* Vtb = (__bf16*)msT_f;   // same size      <= msT slot; dead before wt_k(msT)
    float* Pbuf = (float*)ln_bf;    // M*1024 fp32 partial (ln_bf+o_bf slots, dead at step 9)

    // 0. weight transposes needed before flash (zero-filled past K)
    wt_k<false><<<dim3(34, 96),  256, 0, stream>>>(w_qkv, 1025, 3072, qkvT, 1088);
    wt_k<false><<<dim3(34, 32),  256, 0, stream>>>(w_ap,  1040, 1024, apT,  1088);

    // 1. ln1 = block_norm(project(x)) -> bf16 (stride 1088, zero pad)
    block_norm_bf_k<<<MM, 256, 0, stream>>>(x, 1024, ln_bf, 1088, lnw, lnb, bc);
    // 2. qkv = ln1 @ w_qkv -> fp32 (M,3072)   [128^2 triple-buffer, 2D-XCD]
    mgemm128_k<false, false, false, false><<<dim3(768), 256, 0, stream>>>(
        ln_bf, 1088, qkvT, 1088, nullptr, nullptr, 0, qkvbuf, 3072, 3072, 1088, 24);
    // 3a. RoPE (q in place fp32, Kb bf16) + q/k norms + o_bf pad (cols 1040..1087)
    rope_k<<<MM, 256, 0, stream>>>(qkvbuf, ac, Qt, Kt, Kb, o_bf);
    // 3b. V transpose -> Vtb bf16 + v norms
    vtrans_k<<<dim3(32, 32), 256, 0, stream>>>(qkvbuf, ac, Vtb, Vt);
    // 4. MFMA flash attention -> o_t bf16 (M,1088)
    flash_k<<<dim3(2 * HH, 32), 256, 0, stream>>>(qkvbuf, Kb, Vtb, Qt, Kt, Vt, ac, o_bf);
    // 0b. remaining weight transposes (into the slots Kb/Vtb just vacated)
    wt_k<false><<<dim3(34, 129), 256, 0, stream>>>(w_me,  1025, 4099, meT, 1088);
    wt_k<true ><<<dim3(132, 32), 256, 0, stream>>>(w_ms,  4100, 1024, msT, 4224);  // rotated rows
    // 5. lx2[...,1:] = x + o_t @ w_attn_proj + b -> X2 fp32
    mgemm128_k<true, false, true, false><<<dim3(256), 256, 0, stream>>>(
        o_bf, 1088, apT, 1088, b_ap, x, 1024, X2, 1024, 1024, 1088, 8);
    // 6. ln2 = block_norm(lx2) -> bf16
    block_norm_bf_k<<<MM, 256, 0, stream>>>(X2, 1024, ln_bf, 1088, lnw, lnb, bc);
    // 7. h[0..4095] = gelu(ln2 @ w_mlp_expand + b) -> bf16, ALIGNED offset 0
    mgemm128_k<true, true, false, true><<<dim3(1024), 256, 0, stream>>>(
        ln_bf, 1088, meT, 1088, b_me, nullptr, 0, (void*)h_bf, 4224, 4096, 1088, 32);
    // 8. h cols 4096..4098 (ragged tail) + x0 col 4099 + pad
    row_x0_tail_k<<<MM, 256, 0, stream>>>(h_bf, ln_bf, meT, b_me, mc);
    // 9. P = lx2[...,1:] + h @ w_mlp_shrink(rot) + b -> aligned fp32 (stride 1024)
    mgemm128_k<true, false, true, false><<<dim3(256), 256, 0, stream>>>(
        h_bf, 4224, msT, 4224, b_ms, X2, 1024, (void*)Pbuf, 1024, 1024, 4224, 8);
    // 10. out[...,1:] = P, out[...,0] = x0 (aligned reads, contiguous row writes)
    out_final_k<<<MM, 256, 0, stream>>>(out, Pbuf, bc);
}

// Round 9
// 439.808 us; speedup vs baseline: 1.0534x; 1.0178x over previous
//
#include <hip/hip_runtime.h>
#include <math.h>

// Problem constants: B=2, T=2048, E=1024, H=16, D=64; M = B*T = 4096
#define MM   4096
#define TT   2048
#define HH   16

typedef __bf16 bf16x8 __attribute__((ext_vector_type(8)));
typedef float f32x4 __attribute__((ext_vector_type(4)));

// async global->LDS, 16B per lane; LDS dest = wave-uniform base + lane*16
__device__ __forceinline__ void g2l16(const void* g, void* l) {
    __builtin_amdgcn_global_load_lds(
        (__attribute__((address_space(1))) void*)g,
        (__attribute__((address_space(3))) void*)l, 16, 0, 0);
}

// ---- raw transcendentals (guarded; libm fallback). Without -ffast-math the
// libm versions lower to multi-instruction OCML guard sequences — 3-4x cost.
#if __has_builtin(__builtin_amdgcn_exp2f)
__device__ __forceinline__ float fexp2(float x) { return __builtin_amdgcn_exp2f(x); }
#else
__device__ __forceinline__ float fexp2(float x) { return exp2f(x); }
#endif
#if __has_builtin(__builtin_amdgcn_logf)
__device__ __forceinline__ float flog2(float x) { return __builtin_amdgcn_logf(x); }
#else
__device__ __forceinline__ float flog2(float x) { return log2f(x); }
#endif
#if __has_builtin(__builtin_amdgcn_sqrtf)
__device__ __forceinline__ float fsqrt_(float x) { return __builtin_amdgcn_sqrtf(x); }
#else
__device__ __forceinline__ float fsqrt_(float x) { return sqrtf(x); }
#endif
#if __has_builtin(__builtin_amdgcn_rcpf)
__device__ __forceinline__ float frcp_(float x) { return __builtin_amdgcn_rcpf(x); }
#else
__device__ __forceinline__ float frcp_(float x) { return 1.0f / x; }
#endif
#if __has_builtin(__builtin_amdgcn_rsqf)
__device__ __forceinline__ float frsq_(float x) { return __builtin_amdgcn_rsqf(x); }
#else
__device__ __forceinline__ float frsq_(float x) { return rsqrtf(x); }
#endif

// fast GELU (tanh form, abs err ~1e-3; ref tolerance 0.25 and downstream
// weights are 0.02-scale -> negligible). Replaces libm erff (~35 VALU ops).
__device__ __forceinline__ float gelu_f(float x) {
    float u = 0.7978845608028654f * fmaf(0.044715f * x, x * x, x);
    u = fminf(fmaxf(u, -15.f), 15.f);
    float t = fexp2(-2.885390081777927f * u);     // e^{-2u}
    return 0.5f * x * (1.f + (1.f - t) * frcp_(1.f + t));
}

// ---------------------------------------------------------------- reductions
__device__ __forceinline__ float blockSum256(float v, volatile float* sb) {
    int lane = threadIdx.x & 63, w = threadIdx.x >> 6;
#pragma unroll
    for (int o = 32; o; o >>= 1) v += __shfl_xor(v, o);
    if (lane == 0) sb[w] = v;
    __syncthreads();
    v = sb[0] + sb[1] + sb[2] + sb[3];
    __syncthreads();
    return v;
}

// ---------------------------------------------------------------- block_norm -> bf16 (ldo-wide, zero pad)
__global__ __launch_bounds__(256) void block_norm_bf_k(
    const float* __restrict__ in, int ld,
    __bf16* __restrict__ out, int ldo,
    const float* __restrict__ lw, const float* __restrict__ lb,
    const float* __restrict__ curv)
{
    int row = blockIdx.x;
    const float* x = in + (size_t)row * ld;
    __bf16* o = out + (size_t)row * ldo;
    __shared__ float sb[4];
    int tid = threadIdx.x;
    float v[4]; float s1 = 0.f, s2 = 0.f;
#pragma unroll
    for (int r = 0; r < 4; r++) {
        float t = x[tid + 256 * r];
        v[r] = t; s1 += t; s2 += t * t;
    }
    s1 = blockSum256(s1, sb);
    s2 = blockSum256(s2, sb);
    float mean = s1 * (1.f / 1024.f);
    float var  = s2 * (1.f / 1024.f) - mean * mean;
    float rs = rsqrtf(var + 1e-5f);
    float y[4]; float ssq = 0.f;
#pragma unroll
    for (int r = 0; r < 4; r++) {
        int i = tid + 256 * r;
        float t = (v[r] - mean) * rs * lw[i] + lb[i];
        y[r] = t; ssq += t * t;
    }
    ssq = blockSum256(ssq, sb);
#pragma unroll
    for (int r = 0; r < 4; r++) o[1 + tid + 256 * r] = (__bf16)y[r];
    if (tid == 0) o[0] = (__bf16)sqrtf(expf(*curv) + ssq);
    if (tid < ldo - 1025) o[1025 + tid] = (__bf16)0.f;   // zero pad cols 1025..ldo-1
}

// ---------------------------------------------------------------- final out: copy aligned P -> out[...,1:], x0 col
__global__ __launch_bounds__(256) void out_final_k(
    float* __restrict__ out, const float* __restrict__ P,
    const float* __restrict__ curv)
{
    int row = blockIdx.x;
    const float* p = P + (size_t)row * 1024;
    float* o = out + (size_t)row * 1025;
    __shared__ float sb[4];
    int tid = threadIdx.x;
    float v[4]; float s = 0.f;
#pragma unroll
    for (int r = 0; r < 4; r++) { float t = p[tid + 256 * r]; v[r] = t; s += t * t; }
    s = blockSum256(s, sb);
#pragma unroll
    for (int r = 0; r < 4; r++) o[1 + tid + 256 * r] = v[r];
    if (tid == 0) o[0] = sqrtf(expf(*curv) + s);
}

// ---------------------------------------------------------------- h tail (3 ragged cols) + x0 + pad (stride 4224)
// h layout (permuted, aligned): cols 0..4095 = gelu(h_1..h_4096) [from expand
// GEMM at aligned offset 0], cols 4096..4098 = gelu(h_4097..4099) [here],
// col 4099 = x0, cols 4100..4223 = 0. msT rows rotated to match.
__global__ __launch_bounds__(256) void row_x0_tail_k(
    __bf16* __restrict__ h,
    const __bf16* __restrict__ ln,      // ln2, stride 1088 (zero-padded past 1025)
    const __bf16* __restrict__ Bt,      // meT, stride 1088
    const float* __restrict__ bias,     // b_me (4099)
    const float* __restrict__ curv)
{
    int row = blockIdx.x;
    __bf16* base = h + (size_t)row * 4224;
    const __bf16* lnr = ln + (size_t)row * 1088;
    const __bf16* B0 = Bt + (size_t)4096 * 1088;
    const __bf16* B1 = Bt + (size_t)4097 * 1088;
    const __bf16* B2 = Bt + (size_t)4098 * 1088;
    __shared__ float sb[4];
    float d0 = 0.f, d1 = 0.f, d2 = 0.f;
    for (int i = threadIdx.x; i < 1088; i += 256) {
        float a = (float)lnr[i];
        d0 += a * (float)B0[i];
        d1 += a * (float)B1[i];
        d2 += a * (float)B2[i];
    }
    d0 = blockSum256(d0, sb);
    d1 = blockSum256(d1, sb);
    d2 = blockSum256(d2, sb);
    float t3[3] = {d0 + bias[4096], d1 + bias[4097], d2 + bias[4098]};
    float ssq_t = 0.f;
#pragma unroll
    for (int j = 0; j < 3; j++) {
        float v = gelu_f(t3[j]);
        t3[j] = v; ssq_t += v * v;
    }
    if (threadIdx.x == 0) {
        base[4096] = (__bf16)t3[0];
        base[4097] = (__bf16)t3[1];
        base[4098] = (__bf16)t3[2];
    }
    float s = 0.f;
    for (int i = threadIdx.x; i < 4096; i += 256) { float t = (float)base[i]; s += t * t; }
    s = blockSum256(s, sb) + ssq_t;
    if (threadIdx.x == 0) base[4099] = (__bf16)sqrtf(expf(*curv) + s);   // x0 col
    if (threadIdx.x < 124) base[4100 + threadIdx.x] = (__bf16)0.f;       // zero pad
}

// ---------------------------------------------------------------- weight convert + transpose
// ROT: destination k index rotated by -1 mod K (k=0 -> K-1) — used for msT so
// the augmented x0 row lands at col K-1 and h rows at 0..K-2 (aligned h).
template<bool ROT>
__global__ __launch_bounds__(256) void wt_k(
    const float* __restrict__ W, int K, int N,
    __bf16* __restrict__ Wt, int Kp)
{
    __shared__ float s[32][33];
    int tx = threadIdx.x & 31, ty = threadIdx.x >> 5;    // 32 x 8
    int k0 = blockIdx.x * 32, n0 = blockIdx.y * 32;
#pragma unroll
    for (int r = 0; r < 4; r++) {
        int k = k0 + ty + 8 * r, n = n0 + tx;
        s[ty + 8 * r][tx] = (k < K && n < N) ? W[(size_t)k * N + n] : 0.f;
    }
    __syncthreads();
#pragma unroll
    for (int r = 0; r < 4; r++) {
        int n = n0 + ty + 8 * r, k = k0 + tx;
        int kd = (ROT && k < K) ? ((k == 0) ? (K - 1) : (k - 1)) : k;
        if (n < N) Wt[(size_t)n * Kp + kd] = (__bf16)s[tx][ty + 8 * r];
    }
}

// ---------------------------------------------------------------- bf16 MFMA GEMM 256x256, BK=32, 4-deep RING
// m201-style counted-vmcnt schedule in plain HIP: 512 thr (8 waves, 2Mx4N,
// 128x64 per wave, acc[8][4]); LDS 128KB = 4 sub-buffers x (16KB A + 16KB B)
// at K=32 granularity. Per substage t: issue stage(t+3) (4 g2l16) -> 12
// ds_read_b128 -> setprio + 32 MFMA -> vmcnt(8) -> barrier. Steady state
// keeps 2 stages in flight across barriers (T4); tail drains 8->4->0.
// Swizzle: 16B chunk ^= (row>>1)&3, both-sides. 2D XCD chunking
// (4 m-groups x 2 n-groups). Requires N%256==0, Kp%32==0, NT>=4,
// grid%8==0, (grid/8)%(nT/2)==0.
template<bool BIAS, bool GELU, bool OUTBF>
__global__ __launch_bounds__(512, 2) void mgemm256r_k(
    const __bf16* __restrict__ A, int lda,
    const __bf16* __restrict__ Bt, int ldb,
    const float* __restrict__ bias,
    void* __restrict__ Cout, int ldc,
    int N, int Kp, int nT)
{
    __shared__ __bf16 sAB[65536];   // A: 4 x 8192 elems | B: +32768
    const int tid = threadIdx.x;
    const int w = tid >> 6, lane = tid & 63;
    const int wm = w >> 2, wn = w & 3;
    const int lr = lane & 15, lq = lane >> 4;

    // 2D XCD chunking (bijective)
    const int bid = blockIdx.x;
    const int xcd = bid & 7, loc = bid >> 3;
    const int nH = nT >> 1;
    const int mH = (gridDim.x >> 3) / nH;
    const int mt = (xcd >> 1) * mH + loc / nH;
    const int nt = (xcd & 1) * nH + loc % nH;
    const int m0 = mt * 256, n0 = nt * 256;

    // staging: thread t -> row c*128 + (t>>2), 16B chunk (t&3); src pre-swizzled.
    // LDS dest elem = sub*8192 + c*4096 + 8*t  (linear in t -> wave-uniform base + lane*16B)
    const int rr  = tid >> 2;                       // 0..127
    const int csw = ((tid & 3) ^ ((rr >> 1) & 3)) << 3;   // elems
    const __bf16* gA[2]; const __bf16* gB[2];
#pragma unroll
    for (int c = 0; c < 2; c++) {
        gA[c] = A + (size_t)(m0 + c * 128 + rr) * lda + csw;
        gB[c] = Bt + (size_t)(n0 + c * 128 + rr) * ldb + csw;
    }
    char* lbase = (char*)sAB;
    const int wdst = w * 1024;                      // bytes within (sub, c) slice

    // read offsets: frag row R, chunk = lq ^ ((R>>1)&3); (R>>1)&3 constant over i*16
    const int arowb = wm * 128 + lr;
    const int brow  = wn * 64 + lr;
    const int aoff = ((lq ^ ((arowb >> 1) & 3)) << 3);
    const int boff = ((lq ^ ((brow  >> 1) & 3)) << 3);

    f32x4 zero = {0.f, 0.f, 0.f, 0.f};
    f32x4 acc[8][4];
#pragma unroll
    for (int i = 0; i < 8; i++)
#pragma unroll
        for (int j = 0; j < 4; j++) acc[i][j] = zero;

    const int NTt = Kp >> 5;

    auto stage = [&](int s) {
        const int sb = (s & 3) * 16384;             // bytes
        const int ko = s << 5;                      // elems
#pragma unroll
        for (int c = 0; c < 2; c++) {
            g2l16(gA[c] + ko, lbase + sb + c * 8192 + wdst);
            g2l16(gB[c] + ko, lbase + 65536 + sb + c * 8192 + wdst);
        }
    };

    // prologue: stages 0,1,2 in flight; wait stage 0 landed
    stage(0); stage(1); stage(2);
    asm volatile("s_waitcnt vmcnt(8)" ::: "memory");
    __builtin_amdgcn_s_barrier();

    for (int t = 0; t < NTt; ++t) {
        if (t + 3 < NTt) stage(t + 3);
        const __bf16* pA = sAB + (t & 3) * 8192;
        const __bf16* pB = sAB + 32768 + (t & 3) * 8192;
        bf16x8 af[8], bf[4];
#pragma unroll
        for (int i = 0; i < 8; i++) af[i] = *(const bf16x8*)&pA[(arowb + i * 16) * 32 + aoff];
#pragma unroll
        for (int j = 0; j < 4; j++) bf[j] = *(const bf16x8*)&pB[(brow + j * 16) * 32 + boff];
        __builtin_amdgcn_s_setprio(1);
#pragma unroll
        for (int i = 0; i < 8; i++)
#pragma unroll
            for (int j = 0; j < 4; j++)
                acc[i][j] = __builtin_amdgcn_mfma_f32_16x16x32_bf16(af[i], bf[j], acc[i][j], 0, 0, 0);
        __builtin_amdgcn_s_setprio(0);
        // counted boundary wait: stage(t+1) landed; t+2/t+3 stay in flight
        if (t + 3 < NTt)      { asm volatile("s_waitcnt vmcnt(8)" ::: "memory"); }
        else if (t + 2 < NTt) { asm volatile("s_waitcnt vmcnt(4)" ::: "memory"); }
        else                  { asm volatile("s_waitcnt vmcnt(0) lgkmcnt(0)" ::: "memory"); }
        __builtin_amdgcn_s_barrier();
    }

    // ---- epilogue
#pragma unroll
    for (int j = 0; j < 4; j++) {
        const int n = n0 + wn * 64 + j * 16 + lr;
        if (n < N) {
            const float bv = BIAS ? bias[n] : 0.f;
#pragma unroll
            for (int i = 0; i < 8; i++) {
#pragma unroll
                for (int r = 0; r < 4; r++) {
                    const int m = m0 + wm * 128 + i * 16 + lq * 4 + r;
                    float v = acc[i][j][r] + bv;
                    if (GELU) v = gelu_f(v);
                    if (OUTBF) ((__bf16*)Cout)[(size_t)m * ldc + n] = (__bf16)v;
                    else       ((float*)Cout)[(size_t)m * ldc + n] = v;
                }
            }
        }
    }
}

// ---------------------------------------------------------------- bf16 MFMA GEMM 128x128, BK=32, TRIPLE-buffered
// counted-vmcnt pipeline (T4) + 2D XCD chunking (see R7/R8 notes).
template<bool BIAS, bool GELU, bool SKIP, bool OUTBF>
__global__ __launch_bounds__(256, 3) void mgemm128_k(
    const __bf16* __restrict__ A, int lda,
    const __bf16* __restrict__ Bt, int ldb,
    const float* __restrict__ bias,
    const float* __restrict__ skip, int ldskip,
    void* __restrict__ Cout, int ldc,
    int N, int Kp, int nT)                             // Kp multiple of 32, NT>=3
{
    __shared__ __bf16 sAB[24576];   // A: 3 x 4096 elems | B: 12288 + 3 x 4096
    const int tid = threadIdx.x;
    const int w = tid >> 6, lane = tid & 63;
    const int wm = w >> 1, wn = w & 1;
    const int lr = lane & 15, lq = lane >> 4;

    // 2D XCD chunking (bijective): xcd -> (xm = xcd>>1, xn = xcd&1)
    const int bid = blockIdx.x;
    const int xcd = bid & 7, loc = bid >> 3;
    const int nH = nT >> 1;                         // n-tiles per XCD n-group
    const int mH = (gridDim.x >> 3) / nH;           // m-tiles per XCD m-group
    const int mt = (xcd >> 1) * mH + loc / nH;
    const int nt = (xcd & 1) * nH + loc % nH;
    const int m0 = mt * 128, n0 = nt * 128;

    const int rr  = tid >> 2;                       // 0..63
    const int csw = ((tid & 3) ^ ((rr >> 1) & 3)) << 3;   // elems
    const __bf16* gA[2]; const __bf16* gB[2];
#pragma unroll
    for (int c = 0; c < 2; c++) {
        gA[c] = A + (size_t)(m0 + c * 64 + rr) * lda + csw;
        gB[c] = Bt + (size_t)(n0 + c * 64 + rr) * ldb + csw;
    }
    const int wst = w * 512;                        // wave slice within a load-chunk

    const int off = (lq ^ ((lr >> 1) & 3)) << 3;
    const int arow = wm * 64 + lr;
    const int brow = wn * 64 + lr;

    f32x4 zero = {0.f, 0.f, 0.f, 0.f};
    f32x4 acc[4][4];
#pragma unroll
    for (int i = 0; i < 4; i++)
#pragma unroll
        for (int j = 0; j < 4; j++) acc[i][j] = zero;

    const int NT = Kp >> 5;
    // prologue: stage kt=0 -> buf0, kt=1 -> buf1 (4 loads each)
#pragma unroll
    for (int c = 0; c < 2; c++) {
        g2l16(gA[c], sAB + c * 2048 + wst);
        g2l16(gB[c], sAB + 12288 + c * 2048 + wst);
    }
#pragma unroll
    for (int c = 0; c < 2; c++) {
        g2l16(gA[c] + 32, sAB + 4096 + c * 2048 + wst);
        g2l16(gB[c] + 32, sAB + 12288 + 4096 + c * 2048 + wst);
    }
    asm volatile("s_waitcnt vmcnt(4)" ::: "memory");   // stage0 landed
    __builtin_amdgcn_s_barrier();

    int cur = 0;
    for (int kt = 0; kt < NT; ++kt) {
        if (kt + 2 < NT) {
            const int sbuf = (cur == 0) ? 2 : (cur - 1);      // (cur+2)%3
            const int ko = (kt + 2) << 5;
#pragma unroll
            for (int c = 0; c < 2; c++) {
                g2l16(gA[c] + ko, sAB + sbuf * 4096 + c * 2048 + wst);
                g2l16(gB[c] + ko, sAB + 12288 + sbuf * 4096 + c * 2048 + wst);
            }
        }
        const __bf16* pA = sAB + cur * 4096;
        const __bf16* pB = sAB + 12288 + cur * 4096;
        bf16x8 af[4], bf[4];
#pragma unroll
        for (int i = 0; i < 4; i++) af[i] = *(const bf16x8*)&pA[(arow + i * 16) * 32 + off];
#pragma unroll
        for (int j = 0; j < 4; j++) bf[j] = *(const bf16x8*)&pB[(brow + j * 16) * 32 + off];
        __builtin_amdgcn_s_setprio(1);
#pragma unroll
        for (int i = 0; i < 4; i++)
#pragma unroll
            for (int j = 0; j < 4; j++)
                acc[i][j] = __builtin_amdgcn_mfma_f32_16x16x32_bf16(af[i], bf[j], acc[i][j], 0, 0, 0);
        __builtin_amdgcn_s_setprio(0);
        if (kt + 2 < NT) { asm volatile("s_waitcnt vmcnt(4)" ::: "memory"); }
        else             { asm volatile("s_waitcnt vmcnt(0) lgkmcnt(0)" ::: "memory"); }
        __builtin_amdgcn_s_barrier();
        cur = (cur == 2) ? 0 : (cur + 1);
    }

    // ---- epilogue
#pragma unroll
    for (int j = 0; j < 4; j++) {
        const int n = n0 + wn * 64 + j * 16 + lr;
        if (n < N) {
            const float bv = BIAS ? bias[n] : 0.f;
#pragma unroll
            for (int i = 0; i < 4; i++) {
#pragma unroll
                for (int r = 0; r < 4; r++) {
                    const int m = m0 + wm * 64 + i * 16 + lq * 4 + r;
                    float v = acc[i][j][r] + bv;
                    if (GELU) v = gelu_f(v);
                    if (SKIP) v += skip[(size_t)m * ldskip + n];
                    if (OUTBF) ((__bf16*)Cout)[(size_t)m * ldc + n] = (__bf16)v;
                    else       ((float*)Cout)[(size_t)m * ldc + n] = v;
                }
            }
        }
    }
}

// ---------------------------------------------------------------- RoPE in-place(q) + Kb bf16 + q/k norms
__global__ __launch_bounds__(256) void rope_k(
    float* __restrict__ QKV, const float* __restrict__ curv,
    float* __restrict__ qt, float* __restrict__ kt,
    __bf16* __restrict__ Kb, __bf16* __restrict__ Obf)
{
    int row = blockIdx.x;              // b*T + t
    int b = row >> 11, t = row & (TT - 1);
    int wv = threadIdx.x >> 6, d = threadIdx.x & 63;
    int j = d & 31;
    float fr = (float)t * powf(10000.0f, -(float)(2 * j) / 64.0f);
    float cv = cosf(fr), sv = sinf(fr);
    float sgn = (d < 32) ? sv : -sv;
    for (int h = wv; h < HH; h += 4) {
        float Kh = expf(curv[h]);
        float* base = QKV + (size_t)row * 3072 + h * 64;
        float q = base[d], k = base[1024 + d];
        float qp = __shfl_xor(q, 32);
        float kp = __shfl_xor(k, 32);
        float qr = q * cv + qp * sgn;
        float kr = k * cv + kp * sgn;
        base[d] = qr;                         // q roped in place (fp32 for hi/lo split)
        size_t oidx = ((size_t)(b * HH + h) * TT + t);
        Kb[oidx * 64 + d] = (__bf16)kr;       // roped k, bf16 head-major
        float sq = qr * qr, sk = kr * kr;
#pragma unroll
        for (int o = 32; o; o >>= 1) {
            sq += __shfl_xor(sq, o);
            sk += __shfl_xor(sk, o);
        }
        if (d == 0) {
            qt[oidx] = sqrtf(Kh + sq);
            kt[oidx] = sqrtf(Kh + sk);
        }
    }
    if (threadIdx.x < 48) Obf[(size_t)row * 1088 + 1040 + threadIdx.x] = (__bf16)0.f;
}

// ---------------------------------------------------------------- V transpose -> Vtb bf16 [bh][d][t] + vt norms
__global__ __launch_bounds__(256) void vtrans_k(
    const float* __restrict__ QKV, const float* __restrict__ curv,
    __bf16* __restrict__ Vtb, float* __restrict__ vt)
{
    __shared__ float sT[64 * 65];
    int bh = blockIdx.y; int h = bh & (HH - 1); int b = bh >> 4;
    int t0 = blockIdx.x * 64;
    int tid = threadIdx.x, w = tid >> 6, lane = tid & 63;
    float Kh = expf(curv[h]);
    const float* vbase = QKV + (size_t)(b * TT + t0) * 3072 + 2048 + h * 64;
#pragma unroll 4
    for (int i = 0; i < 16; i++) {
        int tr = w * 16 + i;
        float v = vbase[(size_t)tr * 3072 + lane];
        sT[lane * 65 + tr] = v;
        float s = v * v;
#pragma unroll
        for (int o = 32; o; o >>= 1) s += __shfl_xor(s, o);
        if (lane == 0) vt[(size_t)bh * TT + t0 + tr] = sqrtf(Kh + s);
    }
    __syncthreads();
    int d = tid >> 2, seg = tid & 3;
    const float* r = &sT[d * 65 + seg * 16];
    bf16x8 o0, o1;
#pragma unroll
    for (int i = 0; i < 8; i++) { o0[i] = (__bf16)r[i]; o1[i] = (__bf16)r[8 + i]; }
    __bf16* dst = Vtb + ((size_t)bh * 64 + d) * TT + t0 + seg * 16;
    *(bf16x8*)dst = o0;
    *(bf16x8*)(dst + 8) = o1;
}

// ---------------------------------------------------------------- MFMA flash hyperbolic attention (v7 = R5, proven)
__global__ __launch_bounds__(256, 3) void flash_k(
    const float* __restrict__ QKV,
    const __bf16* __restrict__ Kb, const __bf16* __restrict__ Vtb,
    const float* __restrict__ qt, const float* __restrict__ kt,
    const float* __restrict__ vt,
    const float* __restrict__ curv,
    __bf16* __restrict__ O)
{
    __shared__ __bf16 sK[2][4096];   // [buf][dgrp4][s=64][8 d]
    __shared__ __bf16 sVt[2][4096];  // [buf][tgrp4][d=64][8 t]
    __shared__ __bf16 sP[4 * 16 * 72];
    __shared__ float skt[2][64], svt[2][64];

    int bh = blockIdx.x; int h = bh & (HH - 1); int b = bh >> 4;
    int qti = 31 - (int)blockIdx.y;        // heavy blocks dispatch first
    int q0 = qti << 6;
    int NJ = qti + 1;
    float Kh = expf(curv[h]);
    float sqKh = sqrtf(Kh), msqK = -sqKh, invKh = 1.0f / Kh;
    const float* tok = QKV + (size_t)b * TT * 3072 + h * 64;  // roped q fp32
    const char* KbB = (const char*)Kb + (size_t)bh * TT * 128;
    const char* VtB = (const char*)Vtb + (size_t)bh * 64 * (TT * 2);
    const float* qtp = qt + (size_t)bh * TT;
    const float* ktp = kt + (size_t)bh * TT;
    const float* vtp = vt + (size_t)bh * TT;

    int tid = threadIdx.x;
    int w = tid >> 6, lane = tid & 63;
    int m = lane & 15, quad = lane >> 4;
    int myBase = q0 + 16 * w;              // all 4 waves share the same j-range
    __bf16* sPw = &sP[w * 16 * 72];

    // Q fragments (hi + lo bf16), A-layout: A[m][k=quad*8+j+32*ks]
    bf16x8 qhi[2], qlo[2];
    {
        const float* qrow = tok + (size_t)(myBase + m) * 3072;
#pragma unroll
        for (int ks = 0; ks < 2; ks++) {
            const float* s = qrow + quad * 8 + 32 * ks;
            float4 f0 = *(const float4*)s;
            float4 f1 = *(const float4*)(s + 4);
            float fa[8] = {f0.x, f0.y, f0.z, f0.w, f1.x, f1.y, f1.z, f1.w};
#pragma unroll
            for (int jj = 0; jj < 8; jj++) {
                __bf16 hv = (__bf16)fa[jj];
                qhi[ks][jj] = hv;
                qlo[ks][jj] = (__bf16)(fa[jj] - (float)hv);
            }
        }
    }
    float qtv[4]; int qg[4];
#pragma unroll
    for (int r = 0; r < 4; r++) { qg[r] = myBase + quad * 4 + r; qtv[r] = qtp[qg[r]]; }

    f32x4 zero = {0.f, 0.f, 0.f, 0.f};
    f32x4 accO[4];
#pragma unroll
    for (int nt = 0; nt < 4; nt++) accO[nt] = zero;
    float lsumr[4] = {}, o0r[4] = {};

    // ---- prologue: stage tile 0 -> buf 0
    {
        const char* kg = KbB + (size_t)lane * 128 + w * 16;
        char* sKb = (char*)&sK[0][0] + w * 1024;
        g2l16(kg,      sKb);
        g2l16(kg + 64, sKb + 4096);
        const char* vg = VtB + (size_t)lane * (TT * 2) + w * 16;
        char* sVb = (char*)&sVt[0][0] + w * 1024;
        g2l16(vg,      sVb);
        g2l16(vg + 64, sVb + 4096);
    }
    if (tid < 64) skt[0][tid] = ktp[tid];
    else if (tid < 128) svt[0][tid - 64] = vtp[tid - 64];
    __syncthreads();

    for (int j = 0; j < NJ; ++j) {
        int cur = j & 1;
        int sb = j << 6;
        // ---- issue next-tile stage EARLY (latency hides under compute) ----
        if (j + 1 < NJ) {
            int sb2 = sb + 64;
            const char* kg = KbB + (size_t)(sb2 + lane) * 128 + w * 16;
            char* sKb = (char*)&sK[cur ^ 1][0] + w * 1024;
            g2l16(kg,      sKb);
            g2l16(kg + 64, sKb + 4096);
            const char* vg = VtB + (size_t)lane * (TT * 2) + sb2 * 2 + w * 16;
            char* sVb = (char*)&sVt[cur ^ 1][0] + w * 1024;
            g2l16(vg,      sVb);
            g2l16(vg + 64, sVb + 4096);
            if (tid < 64) skt[cur ^ 1][tid] = ktp[sb2 + tid];
            else if (tid < 128) svt[cur ^ 1][tid - 64] = vtp[sb2 + tid - 64];
        }

        // ---- QK^T: S[16 x 64] ----
        f32x4 accS[4];
#pragma unroll
        for (int nt = 0; nt < 4; nt++) accS[nt] = zero;
#pragma unroll
        for (int nt = 0; nt < 4; nt++) {
#pragma unroll
            for (int ksp = 0; ksp < 2; ksp++) {
                bf16x8 bk = *(const bf16x8*)&sK[cur][((ksp * 4 + quad) * 64 + nt * 16 + m) * 8];
                accS[nt] = __builtin_amdgcn_mfma_f32_16x16x32_bf16(qhi[ksp], bk, accS[nt], 0, 0, 0);
                accS[nt] = __builtin_amdgcn_mfma_f32_16x16x32_bf16(qlo[ksp], bk, accS[nt], 0, 0, 0);
            }
        }
        // ---- score epilogue: hyperbolic logit -> p, raw transcendentals ----
#pragma unroll
        for (int nt = 0; nt < 4; nt++) {
            int col = nt * 16 + m;
            int sglob = sb + col;
            float ktv = skt[cur][col], vtv = svt[cur][col];
#pragma unroll
            for (int r = 0; r < 4; r++) {
                float dot = accS[nt][r];
                float rdiff = fmaf(qtv[r], ktv, -dot);          // qt*kt - q.k
                float ratio = fmaxf(rdiff * invKh, 1.0f + 1e-7f);
                float y = ratio + fsqrt_(fmaf(ratio, ratio, -1.0f));
                float pv = fexp2(msqK * flog2(y));              // exp(-sqrt(K)*acosh)
                float p = (sglob <= qg[r]) ? pv : 0.0f;
                lsumr[r] += p;
                o0r[r] = fmaf(p, vtv, o0r[r]);
                sPw[(quad * 4 + r) * 72 + col] = (__bf16)p;
            }
        }
        __asm__ volatile("s_waitcnt lgkmcnt(0)" ::: "memory");
        // ---- PV: O += P @ V ----
#pragma unroll
        for (int ksp = 0; ksp < 2; ksp++) {
            bf16x8 aP = *(const bf16x8*)&sPw[m * 72 + ksp * 32 + quad * 8];
#pragma unroll
            for (int nt = 0; nt < 4; nt++) {
                bf16x8 bV = *(const bf16x8*)&sVt[cur][((ksp * 4 + quad) * 64 + nt * 16 + m) * 8];
                accO[nt] = __builtin_amdgcn_mfma_f32_16x16x32_bf16(aP, bV, accO[nt], 0, 0, 0);
            }
        }
        __syncthreads();   // drains vmcnt+lgkm: next-tile staging complete, buf reuse safe
    }

    // ---- final: reduce lsum/o0 over the 16 col-lanes, normalize, write ----
#pragma unroll
    for (int r = 0; r < 4; r++) {
#pragma unroll
        for (int off = 1; off < 16; off <<= 1) {
            lsumr[r] += __shfl_xor(lsumr[r], off);
            o0r[r]   += __shfl_xor(o0r[r], off);
        }
    }
#pragma unroll
    for (int r = 0; r < 4; r++) {
        float inv = frcp_(lsumr[r]);
        float o0f = o0r[r] * inv;
        float ov[4]; float part = 0.f;
#pragma unroll
        for (int nt = 0; nt < 4; nt++) { float t = accO[nt][r] * inv; ov[nt] = t; part += t * t; }
        part += __shfl_xor(part, 1);
        part += __shfl_xor(part, 2);
        part += __shfl_xor(part, 4);
        part += __shfl_xor(part, 8);
        float scale = sqKh * frsq_(fmaxf(o0f * o0f - part, 1e-12f));
        size_t orow = (size_t)(b * TT + qg[r]) * 1088 + h * 65;
        if (m == 0) O[orow] = (__bf16)(o0f * scale);
#pragma unroll
        for (int nt = 0; nt < 4; nt++) O[orow + 1 + nt * 16 + m] = (__bf16)(ov[nt] * scale);
    }
}

// ---------------------------------------------------------------- launch
extern "C" void kernel_launch(void* const* d_in, const int* in_sizes, int n_in,
                              void* d_out, int out_size, void* d_ws, size_t ws_size,
                              hipStream_t stream) {
    const float* x    = (const float*)d_in[0];
    const float* bc   = (const float*)d_in[1];
    const float* mc   = (const float*)d_in[2];
    const float* ac   = (const float*)d_in[3];
    const float* w_qkv = (const float*)d_in[4];
    const float* w_ap  = (const float*)d_in[5];
    const float* b_ap  = (const float*)d_in[6];
    const float* w_me  = (const float*)d_in[7];
    const float* b_me  = (const float*)d_in[8];
    const float* w_ms  = (const float*)d_in[9];
    const float* b_ms  = (const float*)d_in[10];
    const float* lnw  = (const float*)d_in[11];
    const float* lnb  = (const float*)d_in[12];
    float* out = (float*)d_out;
    float* ws  = (float*)d_ws;

    // workspace (floats), total ~96.5 MB.
    float* R      = ws;
    float* qkvbuf = R;                             // M*3072 fp32 (dead after flash)
    float* X2     = R;                             // M*1024 fp32 (written step 5)
    __bf16* h_bf  = (__bf16*)(R + 4194304);        // M*4224 bf16 -> ends 12,845,056
    float* p      = R + 12845056;
    __bf16* ln_bf = (__bf16*)p;  p += 2228224;     // M*1088 bf16 (dead after step 8)
    __bf16* o_bf  = (__bf16*)p;  p += 2228224;     // M*1088 bf16 (dead after step 5)
    __bf16* qkvT  = (__bf16*)p;  p += 1671168;     // 3072*1088 bf16
    __bf16* apT   = (__bf16*)p;  p += 557056;      // 1024*1088 bf16
    float*  meT_f = p;           p += 2229856;     // 4099*1088 bf16 (after flash)
    float*  msT_f = p;           p += 2162688;     // 1024*4224 bf16 (after flash)
    float* Qt = p;               p += 2 * HH * TT;
    float* Kt = p;               p += 2 * HH * TT;
    float* Vt = p;
    __bf16* meT = (__bf16*)meT_f;
    __bf16* msT = (__bf16*)msT_f;
    __bf16* Kb  = (__bf16*)meT_f;   // 32*2048*64 bf16 <= meT slot; dead before wt_k(meT)
    __bf16* Vtb = (__bf16*)msT_f;   // same size      <= msT slot; dead before wt_k(msT)
    float* Pbuf = (float*)ln_bf;    // M*1024 fp32 partial (ln_bf+o_bf slots, dead at step 9)

    // 0. weight transposes needed before flash (zero-filled past K)
    wt_k<false><<<dim3(34, 96),  256, 0, stream>>>(w_qkv, 1025, 3072, qkvT, 1088);
    wt_k<false><<<dim3(34, 32),  256, 0, stream>>>(w_ap,  1040, 1024, apT,  1088);

    // 1. ln1 = block_norm(project(x)) -> bf16 (stride 1088, zero pad)
    block_norm_bf_k<<<MM, 256, 0, stream>>>(x, 1024, ln_bf, 1088, lnw, lnb, bc);
    // 2. qkv = ln1 @ w_qkv -> fp32 (M,3072)   [256^2 4-deep RING, 192 blocks]
    mgemm256r_k<false, false, false><<<dim3(192), 512, 0, stream>>>(
        ln_bf, 1088, qkvT, 1088, nullptr, qkvbuf, 3072, 3072, 1088, 12);
    // 3a. RoPE (q in place fp32, Kb bf16) + q/k norms + o_bf pad (cols 1040..1087)
    rope_k<<<MM, 256, 0, stream>>>(qkvbuf, ac, Qt, Kt, Kb, o_bf);
    // 3b. V transpose -> Vtb bf16 + v norms
    vtrans_k<<<dim3(32, 32), 256, 0, stream>>>(qkvbuf, ac, Vtb, Vt);
    // 4. MFMA flash attention -> o_t bf16 (M,1088)
    flash_k<<<dim3(2 * HH, 32), 256, 0, stream>>>(qkvbuf, Kb, Vtb, Qt, Kt, Vt, ac, o_bf);
    // 0b. remaining weight transposes (into the slots Kb/Vtb just vacated)
    wt_k<false><<<dim3(34, 129), 256, 0, stream>>>(w_me,  1025, 4099, meT, 1088);
    wt_k<true ><<<dim3(132, 32), 256, 0, stream>>>(w_ms,  4100, 1024, msT, 4224);  // rotated rows
    // 5. lx2[...,1:] = x + o_t @ w_attn_proj + b -> X2 fp32
    mgemm128_k<true, false, true, false><<<dim3(256), 256, 0, stream>>>(
        o_bf, 1088, apT, 1088, b_ap, x, 1024, X2, 1024, 1024, 1088, 8);
    // 6. ln2 = block_norm(lx2) -> bf16
    block_norm_bf_k<<<MM, 256, 0, stream>>>(X2, 1024, ln_bf, 1088, lnw, lnb, bc);
    // 7. h[0..4095] = gelu(ln2 @ w_mlp_expand + b) -> bf16, ALIGNED   [256^2 RING, 256 blocks]
    mgemm256r_k<true, true, true><<<dim3(256), 512, 0, stream>>>(
        ln_bf, 1088, meT, 1088, b_me, (void*)h_bf, 4224, 4096, 1088, 16);
    // 8. h cols 4096..4098 (ragged tail) + x0 col 4099 + pad
    row_x0_tail_k<<<MM, 256, 0, stream>>>(h_bf, ln_bf, meT, b_me, mc);
    // 9. P = lx2[...,1:] + h @ w_mlp_shrink(rot) + b -> aligned fp32 (stride 1024)
    mgemm128_k<true, false, true, false><<<dim3(256), 256, 0, stream>>>(
        h_bf, 4224, msT, 4224, b_ms, X2, 1024, (void*)Pbuf, 1024, 1024, 4224, 8);
    // 10. out[...,1:] = P, out[...,0] = x0 (aligned reads, contiguous row writes)
    out_final_k<<<MM, 256, 0, stream>>>(out, Pbuf, bc);
}